// Round 10
// baseline (2000.738 us; speedup 1.0000x reference)
//
#include <hip/hip_runtime.h>
#include <hip/hip_bf16.h>
#include <math.h>

// ---------------------------------------------------------------------------
// GIN + JumpingKnowledge(cat) + mean-pool + 2-layer head, eval mode.
// R10: feature-sliced agg for L2 residency. h and z stored slice-major
//      (4 slices x 16 feats; 32 B bf16 / 64 B fp32 per node-slice). agg runs
//      one dispatch per slice: each XCD caches the whole 3.2 MB slice ->
//      gathers hit L2 (~34 TB/s) instead of the ~2 TB/s beyond-L2 path.
//      Lane-pair per edge (32 edges/wave-instr), 2 nodes interleaved.
//      mfma A-load / t0 / h-store / pool re-indexed for the slice layout.
// R9 MFMA MLP (split-bf16 3-term) and binned CSC build unchanged.
// ---------------------------------------------------------------------------

typedef unsigned int uint;
typedef unsigned short ushort;
typedef __attribute__((ext_vector_type(8))) short short8;
typedef __attribute__((ext_vector_type(4))) float floatx4;

#define ABITS 14

__device__ __forceinline__ float bf_lo(uint w) { return __uint_as_float(w << 16); }
__device__ __forceinline__ float bf_hi(uint w) { return __uint_as_float(w & 0xffff0000u); }

__device__ __forceinline__ ushort f2bf(float x) {
  __hip_bfloat16 h = __float2bfloat16(x);
  return *(ushort*)&h;
}
__device__ __forceinline__ float bf2f(ushort u) { return __uint_as_float((uint)u << 16); }

__device__ __forceinline__ void split8(float4 u0, float4 u1, short8& hi, short8& lo) {
  float v0 = u0.x, v1 = u0.y, v2 = u0.z, v3 = u0.w;
  float v4 = u1.x, v5 = u1.y, v6 = u1.z, v7 = u1.w;
  ushort h0 = f2bf(v0), h1 = f2bf(v1), h2 = f2bf(v2), h3 = f2bf(v3);
  ushort h4 = f2bf(v4), h5 = f2bf(v5), h6 = f2bf(v6), h7 = f2bf(v7);
  hi[0] = (short)h0; hi[1] = (short)h1; hi[2] = (short)h2; hi[3] = (short)h3;
  hi[4] = (short)h4; hi[5] = (short)h5; hi[6] = (short)h6; hi[7] = (short)h7;
  lo[0] = (short)f2bf(v0 - bf2f(h0)); lo[1] = (short)f2bf(v1 - bf2f(h1));
  lo[2] = (short)f2bf(v2 - bf2f(h2)); lo[3] = (short)f2bf(v3 - bf2f(h3));
  lo[4] = (short)f2bf(v4 - bf2f(h4)); lo[5] = (short)f2bf(v5 - bf2f(h5));
  lo[6] = (short)f2bf(v6 - bf2f(h6)); lo[7] = (short)f2bf(v7 - bf2f(h7));
}

__global__ void count_deg_kernel(const int* __restrict__ dst, int* __restrict__ deg, int E) {
  int t = blockIdx.x * blockDim.x + threadIdx.x;
  if (t < E) atomicAdd(&deg[dst[t]], 1);
}

__global__ void scan_blocksums(const int* __restrict__ deg, int* __restrict__ bsum, int N) {
  __shared__ int red[256];
  int i = blockIdx.x * 256 + threadIdx.x;
  red[threadIdx.x] = (i < N) ? deg[i] : 0;
  __syncthreads();
  for (int off = 128; off > 0; off >>= 1) {
    if (threadIdx.x < off) red[threadIdx.x] += red[threadIdx.x + off];
    __syncthreads();
  }
  if (threadIdx.x == 0) bsum[blockIdx.x] = red[0];
}

__global__ void scan_bsum(const int* __restrict__ bsum, int* __restrict__ boff,
                          int* __restrict__ rp_last, int B) {
  __shared__ int tmp[1024];
  int t = threadIdx.x;
  int v = (t < B) ? bsum[t] : 0;
  tmp[t] = v;
  __syncthreads();
  for (int off = 1; off < 1024; off <<= 1) {
    int u = (t >= off) ? tmp[t - off] : 0;
    __syncthreads();
    tmp[t] += u;
    __syncthreads();
  }
  if (t < B) boff[t] = tmp[t] - v;
  if (t == 1023) *rp_last = tmp[1023];
}

__global__ void scan_final(const int* __restrict__ deg, const int* __restrict__ boff,
                           int* __restrict__ rp, int* __restrict__ cursor, int N) {
  __shared__ int tmp[256];
  int i = blockIdx.x * 256 + threadIdx.x;
  int v = (i < N) ? deg[i] : 0;
  tmp[threadIdx.x] = v;
  __syncthreads();
  for (int off = 1; off < 256; off <<= 1) {
    int u = (threadIdx.x >= off) ? tmp[threadIdx.x - off] : 0;
    __syncthreads();
    tmp[threadIdx.x] += u;
    __syncthreads();
  }
  if (i < N) {
    int ex = boff[blockIdx.x] + tmp[threadIdx.x] - v;
    rp[i] = ex;
    cursor[i] = ex;
  }
}

__global__ void init_buckets_kernel(const int* __restrict__ rp, int* __restrict__ bc,
                                    int N, int P) {
  int b = threadIdx.x;
  if (b < P) {
    int lo = b << ABITS;
    if (lo > N) lo = N;
    bc[b] = rp[lo];
  }
}

__global__ __launch_bounds__(1024) void bin_edges_kernel(
    const int* __restrict__ src, const int* __restrict__ dst, int* __restrict__ bc,
    int* __restrict__ arena_src, int* __restrict__ arena_dst, int E) {
  __shared__ int cnt[32], base[32];
  for (long chunk = (long)blockIdx.x * 4096; chunk < E; chunk += (long)gridDim.x * 4096) {
    if (threadIdx.x < 32) cnt[threadIdx.x] = 0;
    __syncthreads();
    int s[4], d[4], b[4], r[4];
#pragma unroll
    for (int u = 0; u < 4; ++u) {
      long e = chunk + threadIdx.x + u * 1024;
      if (e < E) {
        s[u] = src[e];
        d[u] = dst[e];
        b[u] = d[u] >> ABITS;
        r[u] = atomicAdd(&cnt[b[u]], 1);
      }
    }
    __syncthreads();
    if (threadIdx.x < 32) base[threadIdx.x] = cnt[threadIdx.x] ? atomicAdd(&bc[threadIdx.x], cnt[threadIdx.x]) : 0;
    __syncthreads();
#pragma unroll
    for (int u = 0; u < 4; ++u) {
      long e = chunk + threadIdx.x + u * 1024;
      if (e < E) {
        int pos = base[b[u]] + r[u];
        arena_src[pos] = s[u];
        arena_dst[pos] = d[u];
      }
    }
    __syncthreads();
  }
}

__global__ void scatter_bucket_kernel(const int* __restrict__ arena_src,
                                      const int* __restrict__ arena_dst,
                                      const int* __restrict__ rp, int* __restrict__ cursor,
                                      int* __restrict__ col, int lo_node, int hi_node) {
  int start = rp[lo_node], end = rp[hi_node];
  for (int i = start + (int)(blockIdx.x * blockDim.x + threadIdx.x); i < end;
       i += (int)(gridDim.x * blockDim.x)) {
    int s = arena_src[i], d = arena_dst[i];
    int pos = atomicAdd(&cursor[d], 1);
    col[pos] = s;
  }
}

__global__ void graph_bounds_kernel(const int* __restrict__ batch, int* __restrict__ gs,
                                    int N, int G) {
  int n = blockIdx.x * 256 + threadIdx.x;
  if (n >= N) return;
  int b = batch[n];
  int bp = (n == 0) ? -1 : batch[n - 1];
  for (int g = bp + 1; g <= b; ++g) gs[g] = n;
  if (n == N - 1)
    for (int g = b + 1; g <= G; ++g) gs[g] = N;
}

// Prepack W1/W2 into MFMA B-fragment order, split hi/lo bf16.
__global__ void prepack_w_kernel(const float* __restrict__ W1_rest,
                                 const float* __restrict__ W2, ushort* __restrict__ wp) {
  int l = blockIdx.x >> 1, g = blockIdx.x & 1;
  const float* W;
  if (g == 0) {
    if (l == 0) return;
    W = W1_rest + (size_t)(l - 1) * 4096;
  } else {
    W = W2 + (size_t)l * 4096;
  }
  ushort* out = wp + (size_t)(l * 2 + g) * 8192;
  for (int idx = threadIdx.x; idx < 4096; idx += blockDim.x) {
    int j = idx & 7, lane = (idx >> 3) & 63, ks = (idx >> 9) & 1, nt = (idx >> 10) & 3;
    int k = ks * 32 + (lane >> 4) * 8 + j;
    int n = nt * 16 + (lane & 15);
    float w = W[k * 64 + n];
    ushort hi = f2bf(w);
    ushort lo = f2bf(w - bf2f(hi));
    size_t base = (size_t)((nt * 2 + ks) * 2) * 512 + lane * 8 + j;
    out[base] = hi;
    out[base + 512] = lo;
  }
}

// Slice-major aggregation: one dispatch per 16-feature slice (3.2 MB table,
// L2-resident per XCD). Lane-pair per edge: 32 edges per wave-instruction.
// 2 nodes interleaved per wave for 2 independent gather chains.
__global__ __launch_bounds__(256, 6) void agg_slice_kernel(
    const ushort* __restrict__ hs, const int* __restrict__ rp,
    const int* __restrict__ col, const float* __restrict__ eps,
    int layer, int slice, float* __restrict__ zs, int N) {
  int lane = threadIdx.x & 63;
  int pair = lane >> 1, hf = lane & 1;
  int wave = blockIdx.x * (blockDim.x >> 6) + (threadIdx.x >> 6);
  int nwaves = gridDim.x * (blockDim.x >> 6);
  float ep = 1.0f + eps[layer];
  const ushort* hsl = hs + (size_t)slice * N * 16;
  float* zsl = zs + (size_t)slice * N * 16;
  for (int n = wave * 2; n < N; n += nwaves * 2) {
    int n0 = __builtin_amdgcn_readfirstlane(n);
    int n1 = n0 + 1;
    int beg0 = rp[n0], end0 = rp[n0 + 1];
    int end1 = (n1 < N) ? rp[n1 + 1] : end0;
    float a[8] = {0.f, 0.f, 0.f, 0.f, 0.f, 0.f, 0.f, 0.f};
    float b[8] = {0.f, 0.f, 0.f, 0.f, 0.f, 0.f, 0.f, 0.f};
    int e0 = beg0 + pair;
    int e1 = end0 + pair;
    while (e0 < end0 || e1 < end1) {
      if (e0 < end0) {
        int s = col[e0];
        uint4 w = *(const uint4*)(hsl + (size_t)s * 16 + hf * 8);
        a[0] += bf_lo(w.x); a[1] += bf_hi(w.x);
        a[2] += bf_lo(w.y); a[3] += bf_hi(w.y);
        a[4] += bf_lo(w.z); a[5] += bf_hi(w.z);
        a[6] += bf_lo(w.w); a[7] += bf_hi(w.w);
      }
      if (e1 < end1) {
        int s = col[e1];
        uint4 w = *(const uint4*)(hsl + (size_t)s * 16 + hf * 8);
        b[0] += bf_lo(w.x); b[1] += bf_hi(w.x);
        b[2] += bf_lo(w.y); b[3] += bf_hi(w.y);
        b[4] += bf_lo(w.z); b[5] += bf_hi(w.z);
        b[6] += bf_lo(w.w); b[7] += bf_hi(w.w);
      }
      e0 += 32; e1 += 32;
    }
    // reduce across the 32 lane-pairs (masks preserve hf bit)
#pragma unroll
    for (int m = 2; m <= 32; m <<= 1) {
#pragma unroll
      for (int j = 0; j < 8; ++j) {
        a[j] += __shfl_xor(a[j], m, 64);
        b[j] += __shfl_xor(b[j], m, 64);
      }
    }
    if (pair == 0) {  // lanes 0,1 write node n0 (hf selects 8-feat half)
      uint4 hv = *(const uint4*)(hsl + (size_t)n0 * 16 + hf * 8);
      float4 z0, z1;
      z0.x = fmaf(ep, bf_lo(hv.x), a[0]); z0.y = fmaf(ep, bf_hi(hv.x), a[1]);
      z0.z = fmaf(ep, bf_lo(hv.y), a[2]); z0.w = fmaf(ep, bf_hi(hv.y), a[3]);
      z1.x = fmaf(ep, bf_lo(hv.z), a[4]); z1.y = fmaf(ep, bf_hi(hv.z), a[5]);
      z1.z = fmaf(ep, bf_lo(hv.w), a[6]); z1.w = fmaf(ep, bf_hi(hv.w), a[7]);
      float4* zr = (float4*)(zsl + (size_t)n0 * 16 + hf * 8);
      zr[0] = z0; zr[1] = z1;
    } else if (pair == 1 && n1 < N) {  // lanes 2,3 write node n1
      uint4 hv = *(const uint4*)(hsl + (size_t)n1 * 16 + hf * 8);
      float4 z0, z1;
      z0.x = fmaf(ep, bf_lo(hv.x), b[0]); z0.y = fmaf(ep, bf_hi(hv.x), b[1]);
      z0.z = fmaf(ep, bf_lo(hv.y), b[2]); z0.w = fmaf(ep, bf_hi(hv.y), b[3]);
      z1.x = fmaf(ep, bf_lo(hv.z), b[4]); z1.y = fmaf(ep, bf_hi(hv.z), b[5]);
      z1.z = fmaf(ep, bf_lo(hv.w), b[6]); z1.w = fmaf(ep, bf_hi(hv.w), b[7]);
      float4* zr = (float4*)(zsl + (size_t)n1 * 16 + hf * 8);
      zr[0] = z0; zr[1] = z1;
    }
  }
}

// MFMA MLP (R9), A-loads / h-stores adapted to slice-major layouts.
__global__ __launch_bounds__(256) void mfma_mlp_kernel(
    const float* __restrict__ zin, ushort* __restrict__ hout,
    const ushort* __restrict__ wp1, const ushort* __restrict__ wp2,
    const float* __restrict__ b1, const float* __restrict__ g1,
    const float* __restrict__ be1, const float* __restrict__ m1,
    const float* __restrict__ v1,
    const float* __restrict__ b2, const float* __restrict__ g2,
    const float* __restrict__ be2, const float* __restrict__ m2,
    const float* __restrict__ v2, int skip1, int N) {
  __shared__ float bnp[6][64];
  __shared__ float tls[4][16][68];
  int tid = threadIdx.x;
  if (tid < 64) {
    bnp[0][tid] = b1[tid];
    float s1 = g1[tid] * rsqrtf(v1[tid] + 1e-5f);
    bnp[1][tid] = s1;
    bnp[2][tid] = be1[tid] - m1[tid] * s1;
    bnp[3][tid] = b2[tid];
    float s2 = g2[tid] * rsqrtf(v2[tid] + 1e-5f);
    bnp[4][tid] = s2;
    bnp[5][tid] = be2[tid] - m2[tid] * s2;
  }
  __syncthreads();
  int wave = tid >> 6, lane = tid & 63;
  int q = lane >> 4, c = lane & 15;
  int base = blockIdx.x * 64 + wave * 16;

  short8 ahi0, alo0, ahi1, alo1;
  {
    long row = base + c;
    if (row >= N) row = N - 1;
    // feats q*8..q*8+7 -> slice q>>1, offset (q&1)*8 ; feats 32+q*8 -> slice 2+(q>>1)
    const float* p0 = zin + (size_t)(q >> 1) * N * 16 + row * 16 + (q & 1) * 8;
    float4 u0 = *(const float4*)p0;
    float4 u1 = *(const float4*)(p0 + 4);
    split8(u0, u1, ahi0, alo0);
    const float* p1 = zin + (size_t)(2 + (q >> 1)) * N * 16 + row * 16 + (q & 1) * 8;
    u0 = *(const float4*)p1;
    u1 = *(const float4*)(p1 + 4);
    split8(u0, u1, ahi1, alo1);
  }

  if (!skip1) {
    floatx4 acc[4];
#pragma unroll
    for (int nt = 0; nt < 4; ++nt) acc[nt] = (floatx4){0.f, 0.f, 0.f, 0.f};
#pragma unroll
    for (int nt = 0; nt < 4; ++nt) {
#pragma unroll
      for (int ks = 0; ks < 2; ++ks) {
        const ushort* fb = wp1 + ((nt * 2 + ks) * 2) * 512 + lane * 8;
        short8 bh = *(const short8*)fb;
        short8 bl = *(const short8*)(fb + 512);
        short8 ah = ks ? ahi1 : ahi0;
        short8 al = ks ? alo1 : alo0;
        acc[nt] = __builtin_amdgcn_mfma_f32_16x16x32_bf16(ah, bh, acc[nt], 0, 0, 0);
        acc[nt] = __builtin_amdgcn_mfma_f32_16x16x32_bf16(al, bh, acc[nt], 0, 0, 0);
        acc[nt] = __builtin_amdgcn_mfma_f32_16x16x32_bf16(ah, bl, acc[nt], 0, 0, 0);
      }
    }
#pragma unroll
    for (int nt = 0; nt < 4; ++nt) {
      int feat = nt * 16 + c;
      float s1 = bnp[1][feat], o1 = bnp[2][feat], bb = bnp[0][feat];
#pragma unroll
      for (int r = 0; r < 4; ++r) {
        float y = fmaxf(acc[nt][r] + bb, 0.f);
        tls[wave][q * 4 + r][feat] = fmaf(y, s1, o1);
      }
    }
    float4 u0 = *(const float4*)&tls[wave][c][q * 8];
    float4 u1 = *(const float4*)&tls[wave][c][q * 8 + 4];
    split8(u0, u1, ahi0, alo0);
    u0 = *(const float4*)&tls[wave][c][32 + q * 8];
    u1 = *(const float4*)&tls[wave][c][32 + q * 8 + 4];
    split8(u0, u1, ahi1, alo1);
  }

  floatx4 acc2[4];
#pragma unroll
  for (int nt = 0; nt < 4; ++nt) acc2[nt] = (floatx4){0.f, 0.f, 0.f, 0.f};
#pragma unroll
  for (int nt = 0; nt < 4; ++nt) {
#pragma unroll
    for (int ks = 0; ks < 2; ++ks) {
      const ushort* fb = wp2 + ((nt * 2 + ks) * 2) * 512 + lane * 8;
      short8 bh = *(const short8*)fb;
      short8 bl = *(const short8*)(fb + 512);
      short8 ah = ks ? ahi1 : ahi0;
      short8 al = ks ? alo1 : alo0;
      acc2[nt] = __builtin_amdgcn_mfma_f32_16x16x32_bf16(ah, bh, acc2[nt], 0, 0, 0);
      acc2[nt] = __builtin_amdgcn_mfma_f32_16x16x32_bf16(al, bh, acc2[nt], 0, 0, 0);
      acc2[nt] = __builtin_amdgcn_mfma_f32_16x16x32_bf16(ah, bl, acc2[nt], 0, 0, 0);
    }
  }
#pragma unroll
  for (int nt = 0; nt < 4; ++nt) {
    int feat = nt * 16 + c;
    float s2 = bnp[4][feat], o2 = bnp[5][feat], bb = bnp[3][feat];
#pragma unroll
    for (int r = 0; r < 4; ++r) {
      int node = base + q * 4 + r;
      if (node < N) {
        float y = fmaxf(acc2[nt][r] + bb, 0.f);
        // slice-major h: slice = nt, offset = c
        hout[(size_t)nt * N * 16 + (size_t)node * 16 + c] = f2bf(fmaf(y, s2, o2));
      }
    }
  }
}

__global__ void z0_kernel(const float* __restrict__ x, const int* __restrict__ rp,
                          const int* __restrict__ col, const float* __restrict__ eps,
                          float* __restrict__ z0, int N) {
  int n = blockIdx.x * blockDim.x + threadIdx.x;
  if (n >= N) return;
  int beg = rp[n], end = rp[n + 1];
  float a = 0.f;
  for (int e = beg; e < end; ++e) a += x[col[e]];
  z0[n] = fmaf(1.0f + eps[0], x[n], a);
}

// layer0 t in slice-major fp32 (feeds mfma GEMM2-only mode)
__global__ void t0_kernel(const float* __restrict__ z0, const float* __restrict__ W1f,
                          const float* __restrict__ b1, const float* __restrict__ g1,
                          const float* __restrict__ be1, const float* __restrict__ m1,
                          const float* __restrict__ v1, float* __restrict__ t, int N) {
  int idx = blockIdx.x * blockDim.x + threadIdx.x;
  if (idx >= N * 64) return;
  int n = idx >> 6, k = idx & 63;
  float s = g1[k] * rsqrtf(v1[k] + 1e-5f);
  float y = fmaxf(fmaf(z0[n], W1f[k], b1[k]), 0.f);
  t[(size_t)(k >> 4) * N * 16 + (size_t)n * 16 + (k & 15)] = fmaf(y, s, be1[k] - m1[k] * s);
}

// pool over slice-major h
__global__ void pool_kernel(const ushort* __restrict__ hb, const int* __restrict__ gs,
                            float* __restrict__ pooled, int layer, int N, int G) {
  int g = blockIdx.x;
  int s = gs[g], e = gs[g + 1];
  int w = threadIdx.x >> 6, lane = threadIdx.x & 63;
  const ushort* hsl = hb + (size_t)(lane >> 4) * N * 16;
  int f = lane & 15;
  float acc = 0.f;
  for (int n = s + w; n < e; n += 4) acc += bf2f(hsl[(size_t)n * 16 + f]);
  __shared__ float red[4][64];
  red[w][lane] = acc;
  __syncthreads();
  if (w == 0)
    pooled[(long)g * 512 + layer * 64 + lane] =
        ((red[0][lane] + red[1][lane]) + (red[2][lane] + red[3][lane]));
}

__global__ __launch_bounds__(64) void final_kernel(
    const float* __restrict__ pooled, const int* __restrict__ gs,
    const float* __restrict__ lin1_w, const float* __restrict__ lin1_b,
    const float* __restrict__ lin2_w, const float* __restrict__ lin2_b,
    float* __restrict__ out, int G) {
  int g = blockIdx.x;
  int j = threadIdx.x;
  float inv = 1.0f / fmaxf((float)(gs[g + 1] - gs[g]), 1.0f);
  __shared__ float p[512];
  for (int t = j; t < 512; t += 64) p[t] = pooled[(long)g * 512 + t] * inv;
  __syncthreads();
  float a0 = lin1_b[j], a1 = 0.f, a2 = 0.f, a3 = 0.f;
  for (int k = 0; k < 512; k += 4) {
    a0 = fmaf(p[k + 0], lin1_w[(k + 0) * 64 + j], a0);
    a1 = fmaf(p[k + 1], lin1_w[(k + 1) * 64 + j], a1);
    a2 = fmaf(p[k + 2], lin1_w[(k + 2) * 64 + j], a2);
    a3 = fmaf(p[k + 3], lin1_w[(k + 3) * 64 + j], a3);
  }
  float hv = fmaxf((a0 + a1) + (a2 + a3), 0.f);
  __shared__ float hb[64];
  hb[j] = hv;
  __syncthreads();
  __shared__ float lg[3];
  if (j < 3) {
    float a = lin2_b[j];
#pragma unroll
    for (int k = 0; k < 64; ++k) a = fmaf(hb[k], lin2_w[k * 3 + j], a);
    lg[j] = a;
  }
  __syncthreads();
  if (j < 3) {
    float mx = fmaxf(fmaxf(lg[0], lg[1]), lg[2]);
    float lse = mx + logf(expf(lg[0] - mx) + expf(lg[1] - mx) + expf(lg[2] - mx));
    out[g * 3 + j] = lg[j] - lse;
  }
}

extern "C" void kernel_launch(void* const* d_in, const int* in_sizes, int n_in,
                              void* d_out, int out_size, void* d_ws, size_t ws_size,
                              hipStream_t stream) {
  const float* x        = (const float*)d_in[0];
  const int*   edge     = (const int*)d_in[1];
  const int*   batch    = (const int*)d_in[2];
  const float* eps      = (const float*)d_in[4];
  const float* W1_first = (const float*)d_in[5];
  const float* W1_rest  = (const float*)d_in[6];
  const float* b1       = (const float*)d_in[7];
  const float* g1       = (const float*)d_in[8];
  const float* be1      = (const float*)d_in[9];
  const float* m1       = (const float*)d_in[10];
  const float* v1       = (const float*)d_in[11];
  const float* W2       = (const float*)d_in[12];
  const float* b2       = (const float*)d_in[13];
  const float* g2       = (const float*)d_in[14];
  const float* be2      = (const float*)d_in[15];
  const float* m2       = (const float*)d_in[16];
  const float* v2       = (const float*)d_in[17];
  const float* lin1_w   = (const float*)d_in[18];
  const float* lin1_b   = (const float*)d_in[19];
  const float* lin2_w   = (const float*)d_in[20];
  const float* lin2_b   = (const float*)d_in[21];

  int N = in_sizes[0];
  int E = in_sizes[1] / 2;
  int G = out_size / 3;
  const int* esrc = edge;
  const int* edst = edge + E;
  int P = (N + (1 << ABITS) - 1) >> ABITS;
  if (P > 32) P = 32;

  size_t off = 0;
  auto alloc = [&](size_t bytes) -> char* {
    char* p = (char*)d_ws + off;
    off += (bytes + 255) & ~(size_t)255;
    return p;
  };
  int SB = (N + 255) / 256;
  int*    deg    = (int*)alloc((size_t)N * 4);
  int*    rp     = (int*)alloc((size_t)(N + 1) * 4);
  int*    cursor = (int*)alloc((size_t)N * 4);
  int*    col    = (int*)alloc((size_t)E * 4);
  int*    bsum   = (int*)alloc((size_t)SB * 4);
  int*    boff   = (int*)alloc((size_t)SB * 4);
  int*    bc     = (int*)alloc((size_t)32 * 4);
  int*    asrc   = (int*)alloc((size_t)E * 4);
  int*    adst   = (int*)alloc((size_t)E * 4);
  int*    gs     = (int*)alloc((size_t)(G + 1) * 4);
  ushort* wpack  = (ushort*)alloc((size_t)16 * 8192 * 2);
  float*  z0buf  = (float*)alloc((size_t)N * 4);
  float*  zbuf   = (float*)alloc((size_t)N * 64 * 4);
  ushort* hA     = (ushort*)alloc((size_t)N * 64 * 2);
  ushort* hB     = (ushort*)alloc((size_t)N * 64 * 2);
  float*  pooled = (float*)alloc((size_t)G * 512 * 4);
  (void)ws_size;

  hipMemsetAsync(deg, 0, (size_t)N * 4, stream);
  int eb = (E + 255) / 256;
  count_deg_kernel<<<eb, 256, 0, stream>>>(edst, deg, E);
  scan_blocksums<<<SB, 256, 0, stream>>>(deg, bsum, N);
  scan_bsum<<<1, 1024, 0, stream>>>(bsum, boff, rp + N, SB);
  scan_final<<<SB, 256, 0, stream>>>(deg, boff, rp, cursor, N);

  init_buckets_kernel<<<1, 64, 0, stream>>>(rp, bc, N, P);
  int ebA = (E + 4095) / 4096;
  bin_edges_kernel<<<ebA, 1024, 0, stream>>>(esrc, edst, bc, asrc, adst, E);
  for (int b = 0; b < P; ++b) {
    int lo = b << ABITS;
    int hi = (b + 1) << ABITS;
    if (hi > N) hi = N;
    if (lo >= N) break;
    scatter_bucket_kernel<<<1024, 256, 0, stream>>>(asrc, adst, rp, cursor, col, lo, hi);
  }

  graph_bounds_kernel<<<SB, 256, 0, stream>>>(batch, gs, N, G);
  prepack_w_kernel<<<16, 256, 0, stream>>>(W1_rest, W2, wpack);

  int nb = (N + 63) / 64;
  z0_kernel<<<SB, 256, 0, stream>>>(x, rp, col, eps, z0buf, N);
  t0_kernel<<<(N * 64 + 255) / 256, 256, 0, stream>>>(z0buf, W1_first, b1, g1, be1, m1, v1,
                                                      zbuf, N);
  mfma_mlp_kernel<<<nb, 256, 0, stream>>>(zbuf, hA, wpack, wpack + 8192,
      b1, g1, be1, m1, v1, b2, g2, be2, m2, v2, 1, N);
  pool_kernel<<<G, 256, 0, stream>>>(hA, gs, pooled, 0, N, G);

  ushort* hin = hA;
  ushort* hout = hB;
  for (int i = 1; i < 8; ++i) {
    for (int s = 0; s < 4; ++s)
      agg_slice_kernel<<<2048, 256, 0, stream>>>(hin, rp, col, eps, i, s, zbuf, N);
    mfma_mlp_kernel<<<nb, 256, 0, stream>>>(zbuf, hout,
        wpack + (size_t)(2 * i) * 8192, wpack + (size_t)(2 * i + 1) * 8192,
        b1 + i * 64, g1 + i * 64, be1 + i * 64, m1 + i * 64, v1 + i * 64,
        b2 + i * 64, g2 + i * 64, be2 + i * 64, m2 + i * 64, v2 + i * 64, 0, N);
    pool_kernel<<<G, 256, 0, stream>>>(hout, gs, pooled, i, N, G);
    ushort* t = hin; hin = hout; hout = t;
  }
  final_kernel<<<G, 64, 0, stream>>>(pooled, gs, lin1_w, lin1_b,
                                     lin2_w, lin2_b, (float*)d_out, G);
}

// Round 11
// 757.260 us; speedup vs baseline: 2.6421x; 2.6421x over previous
//
#include <hip/hip_runtime.h>
#include <hip/hip_bf16.h>
#include <math.h>

// ---------------------------------------------------------------------------
// GIN + JumpingKnowledge(cat) + mean-pool + 2-layer head, eval mode.
// R11: revert R10 slicing (2x cacheline cost per edge: gathers are priced in
//      lines touched, not bytes). R9 structure + atomic-free CSC build:
//      1024-node buckets (NB=98), fixed-capacity arena (no base pre-scan),
//      per-bucket LDS histogram -> deg (replaces count_deg's 1.6M global
//      atomics / 50 MB line ping-pong), per-bucket LDS-cursor scatter -> col
//      (replaces global cursor atomics). Only cold atomics left: bc bucket
//      reservations (391x98, one counter per cacheline).
// R9 MFMA MLP (split-bf16 3-term), R5 agg, pool/final unchanged.
// ---------------------------------------------------------------------------

typedef unsigned int uint;
typedef unsigned short ushort;
typedef __attribute__((ext_vector_type(8))) short short8;
typedef __attribute__((ext_vector_type(4))) float floatx4;

#define BBITS 10                 // 1024 nodes per bucket
#define BCAP 20480               // arena capacity per bucket (mean 16384 + 32 sd)

__device__ __forceinline__ float bf_lo(uint w) { return __uint_as_float(w << 16); }
__device__ __forceinline__ float bf_hi(uint w) { return __uint_as_float(w & 0xffff0000u); }

__device__ __forceinline__ ushort f2bf(float x) {
  __hip_bfloat16 h = __float2bfloat16(x);
  return *(ushort*)&h;
}
__device__ __forceinline__ float bf2f(ushort u) { return __uint_as_float((uint)u << 16); }

__device__ __forceinline__ void split8(float4 u0, float4 u1, short8& hi, short8& lo) {
  float v0 = u0.x, v1 = u0.y, v2 = u0.z, v3 = u0.w;
  float v4 = u1.x, v5 = u1.y, v6 = u1.z, v7 = u1.w;
  ushort h0 = f2bf(v0), h1 = f2bf(v1), h2 = f2bf(v2), h3 = f2bf(v3);
  ushort h4 = f2bf(v4), h5 = f2bf(v5), h6 = f2bf(v6), h7 = f2bf(v7);
  hi[0] = (short)h0; hi[1] = (short)h1; hi[2] = (short)h2; hi[3] = (short)h3;
  hi[4] = (short)h4; hi[5] = (short)h5; hi[6] = (short)h6; hi[7] = (short)h7;
  lo[0] = (short)f2bf(v0 - bf2f(h0)); lo[1] = (short)f2bf(v1 - bf2f(h1));
  lo[2] = (short)f2bf(v2 - bf2f(h2)); lo[3] = (short)f2bf(v3 - bf2f(h3));
  lo[4] = (short)f2bf(v4 - bf2f(h4)); lo[5] = (short)f2bf(v5 - bf2f(h5));
  lo[6] = (short)f2bf(v6 - bf2f(h6)); lo[7] = (short)f2bf(v7 - bf2f(h7));
}

// ---- atomic-free binned CSC build -----------------------------------------

__global__ void init_bc_kernel(int* __restrict__ bc, int NB) {
  int b = threadIdx.x;
  if (b < NB) bc[b * 16] = b * BCAP;  // one cursor per cacheline
}

// partition edges into dst-range buckets; coalesced arena writes.
__global__ __launch_bounds__(1024) void bin_edges_kernel(
    const int* __restrict__ src, const int* __restrict__ dst, int* __restrict__ bc,
    int* __restrict__ arena_src, int* __restrict__ arena_dst, int E) {
  __shared__ int cnt[128], base[128];
  for (long chunk = (long)blockIdx.x * 4096; chunk < E; chunk += (long)gridDim.x * 4096) {
    if (threadIdx.x < 128) cnt[threadIdx.x] = 0;
    __syncthreads();
    int s[4], d[4], b[4], r[4];
#pragma unroll
    for (int u = 0; u < 4; ++u) {
      long e = chunk + threadIdx.x + u * 1024;
      if (e < E) {
        s[u] = src[e];
        d[u] = dst[e];
        b[u] = d[u] >> BBITS;
        r[u] = atomicAdd(&cnt[b[u]], 1);
      }
    }
    __syncthreads();
    if (threadIdx.x < 128)
      base[threadIdx.x] = cnt[threadIdx.x] ? atomicAdd(&bc[threadIdx.x * 16], cnt[threadIdx.x]) : 0;
    __syncthreads();
#pragma unroll
    for (int u = 0; u < 4; ++u) {
      long e = chunk + threadIdx.x + u * 1024;
      if (e < E) {
        int pos = base[b[u]] + r[u];
        arena_src[pos] = s[u];
        arena_dst[pos] = d[u];
      }
    }
    __syncthreads();
  }
}

// one block per bucket: LDS histogram of arena_dst -> deg window (no memset).
__global__ __launch_bounds__(1024) void bucket_count_kernel(
    const int* __restrict__ arena_dst, const int* __restrict__ bc,
    int* __restrict__ deg, int N) {
  __shared__ int hist[1 << BBITS];
  int b = blockIdx.x;
  int lo = b << BBITS;
  int hi = min(lo + (1 << BBITS), N);
  hist[threadIdx.x] = 0;
  __syncthreads();
  int cnt = bc[b * 16] - b * BCAP;
  const int* ad = arena_dst + (size_t)b * BCAP;
  for (int i = threadIdx.x; i < cnt; i += 1024) atomicAdd(&hist[ad[i] - lo], 1);
  __syncthreads();
  if (lo + (int)threadIdx.x < hi) deg[lo + threadIdx.x] = hist[threadIdx.x];
}

// one block per bucket: LDS cursors from rp, scatter col (no global atomics).
__global__ __launch_bounds__(1024) void bucket_scatter_kernel(
    const int* __restrict__ arena_src, const int* __restrict__ arena_dst,
    const int* __restrict__ bc, const int* __restrict__ rp,
    int* __restrict__ col, int N) {
  __shared__ int cur[1 << BBITS];
  int b = blockIdx.x;
  int lo = b << BBITS;
  int hi = min(lo + (1 << BBITS), N);
  if (lo + (int)threadIdx.x < hi) cur[threadIdx.x] = rp[lo + threadIdx.x];
  __syncthreads();
  int cnt = bc[b * 16] - b * BCAP;
  const int* ad = arena_dst + (size_t)b * BCAP;
  const int* as = arena_src + (size_t)b * BCAP;
  for (int i = threadIdx.x; i < cnt; i += 1024) {
    int d = ad[i];
    int pos = atomicAdd(&cur[d - lo], 1);
    col[pos] = as[i];
  }
}

// ---- multi-block exclusive scan: deg[N] -> rp[N+1] ------------------------
__global__ void scan_blocksums(const int* __restrict__ deg, int* __restrict__ bsum, int N) {
  __shared__ int red[256];
  int i = blockIdx.x * 256 + threadIdx.x;
  red[threadIdx.x] = (i < N) ? deg[i] : 0;
  __syncthreads();
  for (int off = 128; off > 0; off >>= 1) {
    if (threadIdx.x < off) red[threadIdx.x] += red[threadIdx.x + off];
    __syncthreads();
  }
  if (threadIdx.x == 0) bsum[blockIdx.x] = red[0];
}

__global__ void scan_bsum(const int* __restrict__ bsum, int* __restrict__ boff,
                          int* __restrict__ rp_last, int B) {
  __shared__ int tmp[1024];
  int t = threadIdx.x;
  int v = (t < B) ? bsum[t] : 0;
  tmp[t] = v;
  __syncthreads();
  for (int off = 1; off < 1024; off <<= 1) {
    int u = (t >= off) ? tmp[t - off] : 0;
    __syncthreads();
    tmp[t] += u;
    __syncthreads();
  }
  if (t < B) boff[t] = tmp[t] - v;
  if (t == 1023) *rp_last = tmp[1023];
}

__global__ void scan_final(const int* __restrict__ deg, const int* __restrict__ boff,
                           int* __restrict__ rp, int N) {
  __shared__ int tmp[256];
  int i = blockIdx.x * 256 + threadIdx.x;
  int v = (i < N) ? deg[i] : 0;
  tmp[threadIdx.x] = v;
  __syncthreads();
  for (int off = 1; off < 256; off <<= 1) {
    int u = (threadIdx.x >= off) ? tmp[threadIdx.x - off] : 0;
    __syncthreads();
    tmp[threadIdx.x] += u;
    __syncthreads();
  }
  if (i < N) rp[i] = boff[blockIdx.x] + tmp[threadIdx.x] - v;
}

__global__ void graph_bounds_kernel(const int* __restrict__ batch, int* __restrict__ gs,
                                    int N, int G) {
  int n = blockIdx.x * 256 + threadIdx.x;
  if (n >= N) return;
  int b = batch[n];
  int bp = (n == 0) ? -1 : batch[n - 1];
  for (int g = bp + 1; g <= b; ++g) gs[g] = n;
  if (n == N - 1)
    for (int g = b + 1; g <= G; ++g) gs[g] = N;
}

// Prepack W1/W2 into MFMA B-fragment order, split hi/lo bf16.
__global__ void prepack_w_kernel(const float* __restrict__ W1_rest,
                                 const float* __restrict__ W2, ushort* __restrict__ wp) {
  int l = blockIdx.x >> 1, g = blockIdx.x & 1;
  const float* W;
  if (g == 0) {
    if (l == 0) return;
    W = W1_rest + (size_t)(l - 1) * 4096;
  } else {
    W = W2 + (size_t)l * 4096;
  }
  ushort* out = wp + (size_t)(l * 2 + g) * 8192;
  for (int idx = threadIdx.x; idx < 4096; idx += blockDim.x) {
    int j = idx & 7, lane = (idx >> 3) & 63, ks = (idx >> 9) & 1, nt = (idx >> 10) & 3;
    int k = ks * 32 + (lane >> 4) * 8 + j;
    int n = nt * 16 + (lane & 15);
    float w = W[k * 64 + n];
    ushort hi = f2bf(w);
    ushort lo = f2bf(w - bf2f(hi));
    size_t base = (size_t)((nt * 2 + ks) * 2) * 512 + lane * 8 + j;
    out[base] = hi;
    out[base + 512] = lo;
  }
}

// z[n][:] = (1+eps_l)*h[n][:] + sum_e h[col[e]][:]   (h bf16 row-major, z fp32)
__global__ __launch_bounds__(256, 6) void agg_kernel(
    const ushort* __restrict__ hb, const int* __restrict__ rp,
    const int* __restrict__ col, const float* __restrict__ eps,
    int layer, float* __restrict__ z, int N) {
  int lane = threadIdx.x & 63;
  int g = lane >> 3;
  int r = lane & 7;
  int wave = blockIdx.x * (blockDim.x >> 6) + (threadIdx.x >> 6);
  int nwaves = gridDim.x * (blockDim.x >> 6);
  float ep = 1.0f + eps[layer];
  for (int n = wave * 2; n < N; n += nwaves * 2) {
    int n0 = __builtin_amdgcn_readfirstlane(n);
    int n1 = n0 + 1;
    int beg0 = rp[n0];
    int end0 = rp[n0 + 1];
    int end1 = (n1 < N) ? rp[n1 + 1] : end0;
    float a0[8] = {0.f, 0.f, 0.f, 0.f, 0.f, 0.f, 0.f, 0.f};
    float a1[8] = {0.f, 0.f, 0.f, 0.f, 0.f, 0.f, 0.f, 0.f};
    float b0[8] = {0.f, 0.f, 0.f, 0.f, 0.f, 0.f, 0.f, 0.f};
    float b1v[8] = {0.f, 0.f, 0.f, 0.f, 0.f, 0.f, 0.f, 0.f};
    int e0 = beg0 + g;
    int e1 = end0 + g;
    while (e0 < end0 || e1 < end1) {
      if (e0 < end0) {
        int s = col[e0];
        uint4 w = ((const uint4*)(hb + (long)s * 64))[r];
        a0[0] += bf_lo(w.x); a0[1] += bf_hi(w.x);
        a0[2] += bf_lo(w.y); a0[3] += bf_hi(w.y);
        a0[4] += bf_lo(w.z); a0[5] += bf_hi(w.z);
        a0[6] += bf_lo(w.w); a0[7] += bf_hi(w.w);
      }
      if (e0 + 8 < end0) {
        int s = col[e0 + 8];
        uint4 w = ((const uint4*)(hb + (long)s * 64))[r];
        a1[0] += bf_lo(w.x); a1[1] += bf_hi(w.x);
        a1[2] += bf_lo(w.y); a1[3] += bf_hi(w.y);
        a1[4] += bf_lo(w.z); a1[5] += bf_hi(w.z);
        a1[6] += bf_lo(w.w); a1[7] += bf_hi(w.w);
      }
      if (e1 < end1) {
        int s = col[e1];
        uint4 w = ((const uint4*)(hb + (long)s * 64))[r];
        b0[0] += bf_lo(w.x); b0[1] += bf_hi(w.x);
        b0[2] += bf_lo(w.y); b0[3] += bf_hi(w.y);
        b0[4] += bf_lo(w.z); b0[5] += bf_hi(w.z);
        b0[6] += bf_lo(w.w); b0[7] += bf_hi(w.w);
      }
      if (e1 + 8 < end1) {
        int s = col[e1 + 8];
        uint4 w = ((const uint4*)(hb + (long)s * 64))[r];
        b1v[0] += bf_lo(w.x); b1v[1] += bf_hi(w.x);
        b1v[2] += bf_lo(w.y); b1v[3] += bf_hi(w.y);
        b1v[4] += bf_lo(w.z); b1v[5] += bf_hi(w.z);
        b1v[6] += bf_lo(w.w); b1v[7] += bf_hi(w.w);
      }
      e0 += 16; e1 += 16;
    }
#pragma unroll
    for (int j = 0; j < 8; ++j) { a0[j] += a1[j]; b0[j] += b1v[j]; }
#pragma unroll
    for (int m = 8; m <= 32; m <<= 1) {
#pragma unroll
      for (int j = 0; j < 8; ++j) {
        a0[j] += __shfl_xor(a0[j], m, 64);
        b0[j] += __shfl_xor(b0[j], m, 64);
      }
    }
    if (g == 0) {
      uint4 hv = ((const uint4*)(hb + (long)n0 * 64))[r];
      float4 z0, z1;
      z0.x = fmaf(ep, bf_lo(hv.x), a0[0]); z0.y = fmaf(ep, bf_hi(hv.x), a0[1]);
      z0.z = fmaf(ep, bf_lo(hv.y), a0[2]); z0.w = fmaf(ep, bf_hi(hv.y), a0[3]);
      z1.x = fmaf(ep, bf_lo(hv.z), a0[4]); z1.y = fmaf(ep, bf_hi(hv.z), a0[5]);
      z1.z = fmaf(ep, bf_lo(hv.w), a0[6]); z1.w = fmaf(ep, bf_hi(hv.w), a0[7]);
      float4* zr = (float4*)(z + (long)n0 * 64 + r * 8);
      zr[0] = z0; zr[1] = z1;
    } else if (g == 1 && n1 < N) {
      uint4 hv = ((const uint4*)(hb + (long)n1 * 64))[r];
      float4 z0, z1;
      z0.x = fmaf(ep, bf_lo(hv.x), b0[0]); z0.y = fmaf(ep, bf_hi(hv.x), b0[1]);
      z0.z = fmaf(ep, bf_lo(hv.y), b0[2]); z0.w = fmaf(ep, bf_hi(hv.y), b0[3]);
      z1.x = fmaf(ep, bf_lo(hv.z), b0[4]); z1.y = fmaf(ep, bf_hi(hv.z), b0[5]);
      z1.z = fmaf(ep, bf_lo(hv.w), b0[6]); z1.w = fmaf(ep, bf_hi(hv.w), b0[7]);
      float4* zr = (float4*)(z + (long)n1 * 64 + r * 8);
      zr[0] = z0; zr[1] = z1;
    }
  }
}

// MFMA MLP (R9): 64 nodes/block, 4 waves x 16-node strip, split-bf16 3-term.
__global__ __launch_bounds__(256) void mfma_mlp_kernel(
    const float* __restrict__ zin, ushort* __restrict__ hout,
    const ushort* __restrict__ wp1, const ushort* __restrict__ wp2,
    const float* __restrict__ b1, const float* __restrict__ g1,
    const float* __restrict__ be1, const float* __restrict__ m1,
    const float* __restrict__ v1,
    const float* __restrict__ b2, const float* __restrict__ g2,
    const float* __restrict__ be2, const float* __restrict__ m2,
    const float* __restrict__ v2, int skip1, int N) {
  __shared__ float bnp[6][64];
  __shared__ float tls[4][16][68];
  int tid = threadIdx.x;
  if (tid < 64) {
    bnp[0][tid] = b1[tid];
    float s1 = g1[tid] * rsqrtf(v1[tid] + 1e-5f);
    bnp[1][tid] = s1;
    bnp[2][tid] = be1[tid] - m1[tid] * s1;
    bnp[3][tid] = b2[tid];
    float s2 = g2[tid] * rsqrtf(v2[tid] + 1e-5f);
    bnp[4][tid] = s2;
    bnp[5][tid] = be2[tid] - m2[tid] * s2;
  }
  __syncthreads();
  int wave = tid >> 6, lane = tid & 63;
  int q = lane >> 4, c = lane & 15;
  int base = blockIdx.x * 64 + wave * 16;

  short8 ahi0, alo0, ahi1, alo1;
  {
    long row = base + c;
    if (row >= N) row = N - 1;
    const float* zr = zin + row * 64;
    float4 u0 = *(const float4*)(zr + q * 8);
    float4 u1 = *(const float4*)(zr + q * 8 + 4);
    split8(u0, u1, ahi0, alo0);
    u0 = *(const float4*)(zr + 32 + q * 8);
    u1 = *(const float4*)(zr + 32 + q * 8 + 4);
    split8(u0, u1, ahi1, alo1);
  }

  if (!skip1) {
    floatx4 acc[4];
#pragma unroll
    for (int nt = 0; nt < 4; ++nt) acc[nt] = (floatx4){0.f, 0.f, 0.f, 0.f};
#pragma unroll
    for (int nt = 0; nt < 4; ++nt) {
#pragma unroll
      for (int ks = 0; ks < 2; ++ks) {
        const ushort* fb = wp1 + ((nt * 2 + ks) * 2) * 512 + lane * 8;
        short8 bh = *(const short8*)fb;
        short8 bl = *(const short8*)(fb + 512);
        short8 ah = ks ? ahi1 : ahi0;
        short8 al = ks ? alo1 : alo0;
        acc[nt] = __builtin_amdgcn_mfma_f32_16x16x32_bf16(ah, bh, acc[nt], 0, 0, 0);
        acc[nt] = __builtin_amdgcn_mfma_f32_16x16x32_bf16(al, bh, acc[nt], 0, 0, 0);
        acc[nt] = __builtin_amdgcn_mfma_f32_16x16x32_bf16(ah, bl, acc[nt], 0, 0, 0);
      }
    }
#pragma unroll
    for (int nt = 0; nt < 4; ++nt) {
      int feat = nt * 16 + c;
      float s1 = bnp[1][feat], o1 = bnp[2][feat], bb = bnp[0][feat];
#pragma unroll
      for (int r = 0; r < 4; ++r) {
        float y = fmaxf(acc[nt][r] + bb, 0.f);
        tls[wave][q * 4 + r][feat] = fmaf(y, s1, o1);
      }
    }
    float4 u0 = *(const float4*)&tls[wave][c][q * 8];
    float4 u1 = *(const float4*)&tls[wave][c][q * 8 + 4];
    split8(u0, u1, ahi0, alo0);
    u0 = *(const float4*)&tls[wave][c][32 + q * 8];
    u1 = *(const float4*)&tls[wave][c][32 + q * 8 + 4];
    split8(u0, u1, ahi1, alo1);
  }

  floatx4 acc2[4];
#pragma unroll
  for (int nt = 0; nt < 4; ++nt) acc2[nt] = (floatx4){0.f, 0.f, 0.f, 0.f};
#pragma unroll
  for (int nt = 0; nt < 4; ++nt) {
#pragma unroll
    for (int ks = 0; ks < 2; ++ks) {
      const ushort* fb = wp2 + ((nt * 2 + ks) * 2) * 512 + lane * 8;
      short8 bh = *(const short8*)fb;
      short8 bl = *(const short8*)(fb + 512);
      short8 ah = ks ? ahi1 : ahi0;
      short8 al = ks ? alo1 : alo0;
      acc2[nt] = __builtin_amdgcn_mfma_f32_16x16x32_bf16(ah, bh, acc2[nt], 0, 0, 0);
      acc2[nt] = __builtin_amdgcn_mfma_f32_16x16x32_bf16(al, bh, acc2[nt], 0, 0, 0);
      acc2[nt] = __builtin_amdgcn_mfma_f32_16x16x32_bf16(ah, bl, acc2[nt], 0, 0, 0);
    }
  }
#pragma unroll
  for (int nt = 0; nt < 4; ++nt) {
    int feat = nt * 16 + c;
    float s2 = bnp[4][feat], o2 = bnp[5][feat], bb = bnp[3][feat];
#pragma unroll
    for (int r = 0; r < 4; ++r) {
      int node = base + q * 4 + r;
      if (node < N) {
        float y = fmaxf(acc2[nt][r] + bb, 0.f);
        hout[(long)node * 64 + feat] = f2bf(fmaf(y, s2, o2));
      }
    }
  }
}

__global__ void z0_kernel(const float* __restrict__ x, const int* __restrict__ rp,
                          const int* __restrict__ col, const float* __restrict__ eps,
                          float* __restrict__ z0, int N) {
  int n = blockIdx.x * blockDim.x + threadIdx.x;
  if (n >= N) return;
  int beg = rp[n], end = rp[n + 1];
  float a = 0.f;
  for (int e = beg; e < end; ++e) a += x[col[e]];
  z0[n] = fmaf(1.0f + eps[0], x[n], a);
}

__global__ void t0_kernel(const float* __restrict__ z0, const float* __restrict__ W1f,
                          const float* __restrict__ b1, const float* __restrict__ g1,
                          const float* __restrict__ be1, const float* __restrict__ m1,
                          const float* __restrict__ v1, float* __restrict__ t, int N) {
  int idx = blockIdx.x * blockDim.x + threadIdx.x;
  if (idx >= N * 64) return;
  int n = idx >> 6, k = idx & 63;
  float s = g1[k] * rsqrtf(v1[k] + 1e-5f);
  float y = fmaxf(fmaf(z0[n], W1f[k], b1[k]), 0.f);
  t[idx] = fmaf(y, s, be1[k] - m1[k] * s);
}

__global__ void pool_kernel(const ushort* __restrict__ hb, const int* __restrict__ gs,
                            float* __restrict__ pooled, int layer, int G) {
  int g = blockIdx.x;
  int s = gs[g], e = gs[g + 1];
  int w = threadIdx.x >> 6, lane = threadIdx.x & 63;
  float acc = 0.f;
  for (int n = s + w; n < e; n += 4) {
    ushort u = hb[(long)n * 64 + lane];
    acc += __uint_as_float((uint)u << 16);
  }
  __shared__ float red[4][64];
  red[w][lane] = acc;
  __syncthreads();
  if (w == 0)
    pooled[(long)g * 512 + layer * 64 + lane] =
        ((red[0][lane] + red[1][lane]) + (red[2][lane] + red[3][lane]));
}

__global__ __launch_bounds__(64) void final_kernel(
    const float* __restrict__ pooled, const int* __restrict__ gs,
    const float* __restrict__ lin1_w, const float* __restrict__ lin1_b,
    const float* __restrict__ lin2_w, const float* __restrict__ lin2_b,
    float* __restrict__ out, int G) {
  int g = blockIdx.x;
  int j = threadIdx.x;
  float inv = 1.0f / fmaxf((float)(gs[g + 1] - gs[g]), 1.0f);
  __shared__ float p[512];
  for (int t = j; t < 512; t += 64) p[t] = pooled[(long)g * 512 + t] * inv;
  __syncthreads();
  float a0 = lin1_b[j], a1 = 0.f, a2 = 0.f, a3 = 0.f;
  for (int k = 0; k < 512; k += 4) {
    a0 = fmaf(p[k + 0], lin1_w[(k + 0) * 64 + j], a0);
    a1 = fmaf(p[k + 1], lin1_w[(k + 1) * 64 + j], a1);
    a2 = fmaf(p[k + 2], lin1_w[(k + 2) * 64 + j], a2);
    a3 = fmaf(p[k + 3], lin1_w[(k + 3) * 64 + j], a3);
  }
  float hv = fmaxf((a0 + a1) + (a2 + a3), 0.f);
  __shared__ float hb[64];
  hb[j] = hv;
  __syncthreads();
  __shared__ float lg[3];
  if (j < 3) {
    float a = lin2_b[j];
#pragma unroll
    for (int k = 0; k < 64; ++k) a = fmaf(hb[k], lin2_w[k * 3 + j], a);
    lg[j] = a;
  }
  __syncthreads();
  if (j < 3) {
    float mx = fmaxf(fmaxf(lg[0], lg[1]), lg[2]);
    float lse = mx + logf(expf(lg[0] - mx) + expf(lg[1] - mx) + expf(lg[2] - mx));
    out[g * 3 + j] = lg[j] - lse;
  }
}

extern "C" void kernel_launch(void* const* d_in, const int* in_sizes, int n_in,
                              void* d_out, int out_size, void* d_ws, size_t ws_size,
                              hipStream_t stream) {
  const float* x        = (const float*)d_in[0];
  const int*   edge     = (const int*)d_in[1];
  const int*   batch    = (const int*)d_in[2];
  const float* eps      = (const float*)d_in[4];
  const float* W1_first = (const float*)d_in[5];
  const float* W1_rest  = (const float*)d_in[6];
  const float* b1       = (const float*)d_in[7];
  const float* g1       = (const float*)d_in[8];
  const float* be1      = (const float*)d_in[9];
  const float* m1       = (const float*)d_in[10];
  const float* v1       = (const float*)d_in[11];
  const float* W2       = (const float*)d_in[12];
  const float* b2       = (const float*)d_in[13];
  const float* g2       = (const float*)d_in[14];
  const float* be2      = (const float*)d_in[15];
  const float* m2       = (const float*)d_in[16];
  const float* v2       = (const float*)d_in[17];
  const float* lin1_w   = (const float*)d_in[18];
  const float* lin1_b   = (const float*)d_in[19];
  const float* lin2_w   = (const float*)d_in[20];
  const float* lin2_b   = (const float*)d_in[21];

  int N = in_sizes[0];
  int E = in_sizes[1] / 2;
  int G = out_size / 3;
  const int* esrc = edge;
  const int* edst = edge + E;
  int NB = (N + (1 << BBITS) - 1) >> BBITS;  // buckets (N=100k -> 98; must be <=128)
  if (NB > 128) NB = 128;

  size_t off = 0;
  auto alloc = [&](size_t bytes) -> char* {
    char* p = (char*)d_ws + off;
    off += (bytes + 255) & ~(size_t)255;
    return p;
  };
  int SB = (N + 255) / 256;
  int*    deg    = (int*)alloc((size_t)N * 4);
  int*    rp     = (int*)alloc((size_t)(N + 1) * 4);
  int*    col    = (int*)alloc((size_t)E * 4);
  int*    bsum   = (int*)alloc((size_t)SB * 4);
  int*    boff   = (int*)alloc((size_t)SB * 4);
  int*    bc     = (int*)alloc((size_t)128 * 16 * 4);
  int*    asrc   = (int*)alloc((size_t)NB * BCAP * 4);
  int*    adst   = (int*)alloc((size_t)NB * BCAP * 4);
  int*    gs     = (int*)alloc((size_t)(G + 1) * 4);
  ushort* wpack  = (ushort*)alloc((size_t)16 * 8192 * 2);
  float*  z0buf  = (float*)alloc((size_t)N * 4);
  float*  zbuf   = (float*)alloc((size_t)N * 64 * 4);
  ushort* hA     = (ushort*)alloc((size_t)N * 64 * 2);
  ushort* hB     = (ushort*)alloc((size_t)N * 64 * 2);
  float*  pooled = (float*)alloc((size_t)G * 512 * 4);
  (void)ws_size;

  // atomic-free binned CSC build
  init_bc_kernel<<<1, 128, 0, stream>>>(bc, NB);
  int ebA = (E + 4095) / 4096;
  bin_edges_kernel<<<ebA, 1024, 0, stream>>>(esrc, edst, bc, asrc, adst, E);
  bucket_count_kernel<<<NB, 1024, 0, stream>>>(adst, bc, deg, N);
  scan_blocksums<<<SB, 256, 0, stream>>>(deg, bsum, N);
  scan_bsum<<<1, 1024, 0, stream>>>(bsum, boff, rp + N, SB);
  scan_final<<<SB, 256, 0, stream>>>(deg, boff, rp, N);
  bucket_scatter_kernel<<<NB, 1024, 0, stream>>>(asrc, adst, bc, rp, col, N);

  graph_bounds_kernel<<<SB, 256, 0, stream>>>(batch, gs, N, G);
  prepack_w_kernel<<<16, 256, 0, stream>>>(W1_rest, W2, wpack);

  int nb = (N + 63) / 64;
  z0_kernel<<<SB, 256, 0, stream>>>(x, rp, col, eps, z0buf, N);
  t0_kernel<<<(N * 64 + 255) / 256, 256, 0, stream>>>(z0buf, W1_first, b1, g1, be1, m1, v1,
                                                      zbuf, N);
  mfma_mlp_kernel<<<nb, 256, 0, stream>>>(zbuf, hA, wpack, wpack + 8192,
      b1, g1, be1, m1, v1, b2, g2, be2, m2, v2, 1, N);
  pool_kernel<<<G, 256, 0, stream>>>(hA, gs, pooled, 0, G);

  ushort* hin = hA;
  ushort* hout = hB;
  for (int i = 1; i < 8; ++i) {
    agg_kernel<<<2048, 256, 0, stream>>>(hin, rp, col, eps, i, zbuf, N);
    mfma_mlp_kernel<<<nb, 256, 0, stream>>>(zbuf, hout,
        wpack + (size_t)(2 * i) * 8192, wpack + (size_t)(2 * i + 1) * 8192,
        b1 + i * 64, g1 + i * 64, be1 + i * 64, m1 + i * 64, v1 + i * 64,
        b2 + i * 64, g2 + i * 64, be2 + i * 64, m2 + i * 64, v2 + i * 64, 0, N);
    pool_kernel<<<G, 256, 0, stream>>>(hout, gs, pooled, i, G);
    ushort* t = hin; hin = hout; hout = t;
  }
  final_kernel<<<G, 64, 0, stream>>>(pooled, gs, lin1_w, lin1_b,
                                     lin2_w, lin2_b, (float*)d_out, G);
}

// Round 13
// 746.258 us; speedup vs baseline: 2.6810x; 1.0147x over previous
//
#include <hip/hip_runtime.h>
#include <hip/hip_bf16.h>
#include <math.h>

// ---------------------------------------------------------------------------
// GIN + JumpingKnowledge(cat) + mean-pool + 2-layer head, eval mode.
// R13 = R12 with the compile fix: nontemporal stores need clang native vector
// types (ext_vector_type), not HIP_vector_type uint4.
//  - z stored bf16 (halves z traffic; GEMM1 2-term A*(Whi+Wlo)); t0 bf16 too.
//  - nontemporal: agg z-stores, col loads, mlp z-loads (stop evicting the
//    12.8MB h table from the 4MiB/XCD L2 -> higher gather hit rate).
//  - pool fused into mfma epilogue (LDS stage + per-graph segment sums +
//    fp32 atomicAdd; pooled memset once per launch). 8 dispatches removed.
// R11 atomic-free CSC build, R9 MFMA structure unchanged.
// ---------------------------------------------------------------------------

typedef unsigned int uint;
typedef unsigned short ushort;
typedef __attribute__((ext_vector_type(8))) short short8;
typedef __attribute__((ext_vector_type(4))) float floatx4;
typedef __attribute__((ext_vector_type(4))) uint uintx4;

#define BBITS 10                 // 1024 nodes per bucket
#define BCAP 20480               // arena capacity per bucket

__device__ __forceinline__ float bf_lo(uint w) { return __uint_as_float(w << 16); }
__device__ __forceinline__ float bf_hi(uint w) { return __uint_as_float(w & 0xffff0000u); }

__device__ __forceinline__ ushort f2bf(float x) {
  __hip_bfloat16 h = __float2bfloat16(x);
  return *(ushort*)&h;
}
__device__ __forceinline__ float bf2f(ushort u) { return __uint_as_float((uint)u << 16); }

__device__ __forceinline__ uint pack_bf16(float a, float b) {
  return (uint)f2bf(a) | ((uint)f2bf(b) << 16);
}

// split 16 fp32 (two 8-chunks) into hi/lo bf16 fragments (used for t in GEMM2)
__device__ __forceinline__ void split8(float4 u0, float4 u1, short8& hi, short8& lo) {
  float v0 = u0.x, v1 = u0.y, v2 = u0.z, v3 = u0.w;
  float v4 = u1.x, v5 = u1.y, v6 = u1.z, v7 = u1.w;
  ushort h0 = f2bf(v0), h1 = f2bf(v1), h2 = f2bf(v2), h3 = f2bf(v3);
  ushort h4 = f2bf(v4), h5 = f2bf(v5), h6 = f2bf(v6), h7 = f2bf(v7);
  hi[0] = (short)h0; hi[1] = (short)h1; hi[2] = (short)h2; hi[3] = (short)h3;
  hi[4] = (short)h4; hi[5] = (short)h5; hi[6] = (short)h6; hi[7] = (short)h7;
  lo[0] = (short)f2bf(v0 - bf2f(h0)); lo[1] = (short)f2bf(v1 - bf2f(h1));
  lo[2] = (short)f2bf(v2 - bf2f(h2)); lo[3] = (short)f2bf(v3 - bf2f(h3));
  lo[4] = (short)f2bf(v4 - bf2f(h4)); lo[5] = (short)f2bf(v5 - bf2f(h5));
  lo[6] = (short)f2bf(v6 - bf2f(h6)); lo[7] = (short)f2bf(v7 - bf2f(h7));
}

// ---- atomic-free binned CSC build -----------------------------------------

__global__ void init_bc_kernel(int* __restrict__ bc, int NB) {
  int b = threadIdx.x;
  if (b < NB) bc[b * 16] = b * BCAP;
}

__global__ __launch_bounds__(1024) void bin_edges_kernel(
    const int* __restrict__ src, const int* __restrict__ dst, int* __restrict__ bc,
    int* __restrict__ arena_src, int* __restrict__ arena_dst, int E) {
  __shared__ int cnt[128], base[128];
  for (long chunk = (long)blockIdx.x * 4096; chunk < E; chunk += (long)gridDim.x * 4096) {
    if (threadIdx.x < 128) cnt[threadIdx.x] = 0;
    __syncthreads();
    int s[4], d[4], b[4], r[4];
#pragma unroll
    for (int u = 0; u < 4; ++u) {
      long e = chunk + threadIdx.x + u * 1024;
      if (e < E) {
        s[u] = src[e];
        d[u] = dst[e];
        b[u] = d[u] >> BBITS;
        r[u] = atomicAdd(&cnt[b[u]], 1);
      }
    }
    __syncthreads();
    if (threadIdx.x < 128)
      base[threadIdx.x] = cnt[threadIdx.x] ? atomicAdd(&bc[threadIdx.x * 16], cnt[threadIdx.x]) : 0;
    __syncthreads();
#pragma unroll
    for (int u = 0; u < 4; ++u) {
      long e = chunk + threadIdx.x + u * 1024;
      if (e < E) {
        int pos = base[b[u]] + r[u];
        arena_src[pos] = s[u];
        arena_dst[pos] = d[u];
      }
    }
    __syncthreads();
  }
}

__global__ __launch_bounds__(1024) void bucket_count_kernel(
    const int* __restrict__ arena_dst, const int* __restrict__ bc,
    int* __restrict__ deg, int N) {
  __shared__ int hist[1 << BBITS];
  int b = blockIdx.x;
  int lo = b << BBITS;
  int hi = min(lo + (1 << BBITS), N);
  hist[threadIdx.x] = 0;
  __syncthreads();
  int cnt = bc[b * 16] - b * BCAP;
  const int* ad = arena_dst + (size_t)b * BCAP;
  for (int i = threadIdx.x; i < cnt; i += 1024) atomicAdd(&hist[ad[i] - lo], 1);
  __syncthreads();
  if (lo + (int)threadIdx.x < hi) deg[lo + threadIdx.x] = hist[threadIdx.x];
}

__global__ __launch_bounds__(1024) void bucket_scatter_kernel(
    const int* __restrict__ arena_src, const int* __restrict__ arena_dst,
    const int* __restrict__ bc, const int* __restrict__ rp,
    int* __restrict__ col, int N) {
  __shared__ int cur[1 << BBITS];
  int b = blockIdx.x;
  int lo = b << BBITS;
  int hi = min(lo + (1 << BBITS), N);
  if (lo + (int)threadIdx.x < hi) cur[threadIdx.x] = rp[lo + threadIdx.x];
  __syncthreads();
  int cnt = bc[b * 16] - b * BCAP;
  const int* ad = arena_dst + (size_t)b * BCAP;
  const int* as = arena_src + (size_t)b * BCAP;
  for (int i = threadIdx.x; i < cnt; i += 1024) {
    int d = ad[i];
    int pos = atomicAdd(&cur[d - lo], 1);
    col[pos] = as[i];
  }
}

// ---- scan -----------------------------------------------------------------
__global__ void scan_blocksums(const int* __restrict__ deg, int* __restrict__ bsum, int N) {
  __shared__ int red[256];
  int i = blockIdx.x * 256 + threadIdx.x;
  red[threadIdx.x] = (i < N) ? deg[i] : 0;
  __syncthreads();
  for (int off = 128; off > 0; off >>= 1) {
    if (threadIdx.x < off) red[threadIdx.x] += red[threadIdx.x + off];
    __syncthreads();
  }
  if (threadIdx.x == 0) bsum[blockIdx.x] = red[0];
}

__global__ void scan_bsum(const int* __restrict__ bsum, int* __restrict__ boff,
                          int* __restrict__ rp_last, int B) {
  __shared__ int tmp[1024];
  int t = threadIdx.x;
  int v = (t < B) ? bsum[t] : 0;
  tmp[t] = v;
  __syncthreads();
  for (int off = 1; off < 1024; off <<= 1) {
    int u = (t >= off) ? tmp[t - off] : 0;
    __syncthreads();
    tmp[t] += u;
    __syncthreads();
  }
  if (t < B) boff[t] = tmp[t] - v;
  if (t == 1023) *rp_last = tmp[1023];
}

__global__ void scan_final(const int* __restrict__ deg, const int* __restrict__ boff,
                           int* __restrict__ rp, int N) {
  __shared__ int tmp[256];
  int i = blockIdx.x * 256 + threadIdx.x;
  int v = (i < N) ? deg[i] : 0;
  tmp[threadIdx.x] = v;
  __syncthreads();
  for (int off = 1; off < 256; off <<= 1) {
    int u = (threadIdx.x >= off) ? tmp[threadIdx.x - off] : 0;
    __syncthreads();
    tmp[threadIdx.x] += u;
    __syncthreads();
  }
  if (i < N) rp[i] = boff[blockIdx.x] + tmp[threadIdx.x] - v;
}

__global__ void graph_bounds_kernel(const int* __restrict__ batch, int* __restrict__ gs,
                                    int N, int G) {
  int n = blockIdx.x * 256 + threadIdx.x;
  if (n >= N) return;
  int b = batch[n];
  int bp = (n == 0) ? -1 : batch[n - 1];
  for (int g = bp + 1; g <= b; ++g) gs[g] = n;
  if (n == N - 1)
    for (int g = b + 1; g <= G; ++g) gs[g] = N;
}

// Prepack W1/W2 into MFMA B-fragment order, split hi/lo bf16.
__global__ void prepack_w_kernel(const float* __restrict__ W1_rest,
                                 const float* __restrict__ W2, ushort* __restrict__ wp) {
  int l = blockIdx.x >> 1, g = blockIdx.x & 1;
  const float* W;
  if (g == 0) {
    if (l == 0) return;
    W = W1_rest + (size_t)(l - 1) * 4096;
  } else {
    W = W2 + (size_t)l * 4096;
  }
  ushort* out = wp + (size_t)(l * 2 + g) * 8192;
  for (int idx = threadIdx.x; idx < 4096; idx += blockDim.x) {
    int j = idx & 7, lane = (idx >> 3) & 63, ks = (idx >> 9) & 1, nt = (idx >> 10) & 3;
    int k = ks * 32 + (lane >> 4) * 8 + j;
    int n = nt * 16 + (lane & 15);
    float w = W[k * 64 + n];
    ushort hi = f2bf(w);
    ushort lo = f2bf(w - bf2f(hi));
    size_t base = (size_t)((nt * 2 + ks) * 2) * 512 + lane * 8 + j;
    out[base] = hi;
    out[base + 512] = lo;
  }
}

// z[n][:] = (1+eps_l)*h[n][:] + sum_e h[col[e]][:]   (h bf16, z bf16 out)
// nt: col loads and z stores bypass-hint L2 (preserve h-table residency).
__global__ __launch_bounds__(256, 6) void agg_kernel(
    const ushort* __restrict__ hb, const int* __restrict__ rp,
    const int* __restrict__ col, const float* __restrict__ eps,
    int layer, ushort* __restrict__ zb, int N) {
  int lane = threadIdx.x & 63;
  int g = lane >> 3;
  int r = lane & 7;
  int wave = blockIdx.x * (blockDim.x >> 6) + (threadIdx.x >> 6);
  int nwaves = gridDim.x * (blockDim.x >> 6);
  float ep = 1.0f + eps[layer];
  for (int n = wave * 2; n < N; n += nwaves * 2) {
    int n0 = __builtin_amdgcn_readfirstlane(n);
    int n1 = n0 + 1;
    int beg0 = rp[n0];
    int end0 = rp[n0 + 1];
    int end1 = (n1 < N) ? rp[n1 + 1] : end0;
    float a0[8] = {0.f, 0.f, 0.f, 0.f, 0.f, 0.f, 0.f, 0.f};
    float a1[8] = {0.f, 0.f, 0.f, 0.f, 0.f, 0.f, 0.f, 0.f};
    float b0[8] = {0.f, 0.f, 0.f, 0.f, 0.f, 0.f, 0.f, 0.f};
    float b1v[8] = {0.f, 0.f, 0.f, 0.f, 0.f, 0.f, 0.f, 0.f};
    int e0 = beg0 + g;
    int e1 = end0 + g;
    while (e0 < end0 || e1 < end1) {
      if (e0 < end0) {
        int s = __builtin_nontemporal_load(col + e0);
        uint4 w = ((const uint4*)(hb + (long)s * 64))[r];
        a0[0] += bf_lo(w.x); a0[1] += bf_hi(w.x);
        a0[2] += bf_lo(w.y); a0[3] += bf_hi(w.y);
        a0[4] += bf_lo(w.z); a0[5] += bf_hi(w.z);
        a0[6] += bf_lo(w.w); a0[7] += bf_hi(w.w);
      }
      if (e0 + 8 < end0) {
        int s = __builtin_nontemporal_load(col + e0 + 8);
        uint4 w = ((const uint4*)(hb + (long)s * 64))[r];
        a1[0] += bf_lo(w.x); a1[1] += bf_hi(w.x);
        a1[2] += bf_lo(w.y); a1[3] += bf_hi(w.y);
        a1[4] += bf_lo(w.z); a1[5] += bf_hi(w.z);
        a1[6] += bf_lo(w.w); a1[7] += bf_hi(w.w);
      }
      if (e1 < end1) {
        int s = __builtin_nontemporal_load(col + e1);
        uint4 w = ((const uint4*)(hb + (long)s * 64))[r];
        b0[0] += bf_lo(w.x); b0[1] += bf_hi(w.x);
        b0[2] += bf_lo(w.y); b0[3] += bf_hi(w.y);
        b0[4] += bf_lo(w.z); b0[5] += bf_hi(w.z);
        b0[6] += bf_lo(w.w); b0[7] += bf_hi(w.w);
      }
      if (e1 + 8 < end1) {
        int s = __builtin_nontemporal_load(col + e1 + 8);
        uint4 w = ((const uint4*)(hb + (long)s * 64))[r];
        b1v[0] += bf_lo(w.x); b1v[1] += bf_hi(w.x);
        b1v[2] += bf_lo(w.y); b1v[3] += bf_hi(w.y);
        b1v[4] += bf_lo(w.z); b1v[5] += bf_hi(w.z);
        b1v[6] += bf_lo(w.w); b1v[7] += bf_hi(w.w);
      }
      e0 += 16; e1 += 16;
    }
#pragma unroll
    for (int j = 0; j < 8; ++j) { a0[j] += a1[j]; b0[j] += b1v[j]; }
#pragma unroll
    for (int m = 8; m <= 32; m <<= 1) {
#pragma unroll
      for (int j = 0; j < 8; ++j) {
        a0[j] += __shfl_xor(a0[j], m, 64);
        b0[j] += __shfl_xor(b0[j], m, 64);
      }
    }
    if (g == 0) {
      uint4 hv = ((const uint4*)(hb + (long)n0 * 64))[r];
      float v0 = fmaf(ep, bf_lo(hv.x), a0[0]), v1 = fmaf(ep, bf_hi(hv.x), a0[1]);
      float v2 = fmaf(ep, bf_lo(hv.y), a0[2]), v3 = fmaf(ep, bf_hi(hv.y), a0[3]);
      float v4 = fmaf(ep, bf_lo(hv.z), a0[4]), v5 = fmaf(ep, bf_hi(hv.z), a0[5]);
      float v6 = fmaf(ep, bf_lo(hv.w), a0[6]), v7 = fmaf(ep, bf_hi(hv.w), a0[7]);
      uintx4 w;
      w.x = pack_bf16(v0, v1); w.y = pack_bf16(v2, v3);
      w.z = pack_bf16(v4, v5); w.w = pack_bf16(v6, v7);
      __builtin_nontemporal_store(w, (uintx4*)(zb + (size_t)n0 * 64 + r * 8));
    } else if (g == 1 && n1 < N) {
      uint4 hv = ((const uint4*)(hb + (long)n1 * 64))[r];
      float v0 = fmaf(ep, bf_lo(hv.x), b0[0]), v1 = fmaf(ep, bf_hi(hv.x), b0[1]);
      float v2 = fmaf(ep, bf_lo(hv.y), b0[2]), v3 = fmaf(ep, bf_hi(hv.y), b0[3]);
      float v4 = fmaf(ep, bf_lo(hv.z), b0[4]), v5 = fmaf(ep, bf_hi(hv.z), b0[5]);
      float v6 = fmaf(ep, bf_lo(hv.w), b0[6]), v7 = fmaf(ep, bf_hi(hv.w), b0[7]);
      uintx4 w;
      w.x = pack_bf16(v0, v1); w.y = pack_bf16(v2, v3);
      w.z = pack_bf16(v4, v5); w.w = pack_bf16(v6, v7);
      __builtin_nontemporal_store(w, (uintx4*)(zb + (size_t)n1 * 64 + r * 8));
    }
  }
}

// ---------------------------------------------------------------------------
// MFMA MLP + fused mean-pool partial sums.
// 64 nodes/block, 4 waves x 16-node strip. z is bf16 (A direct, GEMM1 2-term
// A*(Whi)+A*(Wlo)); t fp32 in LDS, split hi/lo, GEMM2 3-term (or 2-term in
// skip1 mode where A comes from global bf16 t). Epilogue: bn2 -> h bf16 store
// + LDS stage -> per-graph segment sums -> fp32 atomicAdd into pooled.
// ---------------------------------------------------------------------------
__global__ __launch_bounds__(256) void mfma_mlp_kernel(
    const ushort* __restrict__ zb, ushort* __restrict__ hout,
    const ushort* __restrict__ wp1, const ushort* __restrict__ wp2,
    const float* __restrict__ b1, const float* __restrict__ g1,
    const float* __restrict__ be1, const float* __restrict__ m1,
    const float* __restrict__ v1,
    const float* __restrict__ b2, const float* __restrict__ g2,
    const float* __restrict__ be2, const float* __restrict__ m2,
    const float* __restrict__ v2,
    const int* __restrict__ batch, float* __restrict__ pooled,
    int layer, int skip1, int N) {
  __shared__ float bnp[6][64];
  __shared__ float tls[4][16][68];
  __shared__ float hls[64][68];
  __shared__ int batchl[64];
  int tid = threadIdx.x;
  int blockbase = blockIdx.x * 64;
  if (tid < 64) {
    bnp[0][tid] = b1[tid];
    float s1 = g1[tid] * rsqrtf(v1[tid] + 1e-5f);
    bnp[1][tid] = s1;
    bnp[2][tid] = be1[tid] - m1[tid] * s1;
    bnp[3][tid] = b2[tid];
    float s2 = g2[tid] * rsqrtf(v2[tid] + 1e-5f);
    bnp[4][tid] = s2;
    bnp[5][tid] = be2[tid] - m2[tid] * s2;
    batchl[tid] = (blockbase + tid < N) ? batch[blockbase + tid] : -1;
  }
  __syncthreads();
  int wave = tid >> 6, lane = tid & 63;
  int q = lane >> 4, c = lane & 15;
  int base = blockbase + wave * 16;

  // A fragments from global bf16 z (nontemporal: single-use stream)
  short8 ahi0, alo0, ahi1, alo1;
  {
    long row = base + c;
    if (row >= N) row = N - 1;
    const ushort* zr = zb + row * 64;
    ahi0 = __builtin_nontemporal_load((const short8*)(zr + q * 8));
    ahi1 = __builtin_nontemporal_load((const short8*)(zr + 32 + q * 8));
  }

  if (!skip1) {
    floatx4 acc[4];
#pragma unroll
    for (int nt = 0; nt < 4; ++nt) acc[nt] = (floatx4){0.f, 0.f, 0.f, 0.f};
#pragma unroll
    for (int nt = 0; nt < 4; ++nt) {
#pragma unroll
      for (int ks = 0; ks < 2; ++ks) {
        const ushort* fb = wp1 + ((nt * 2 + ks) * 2) * 512 + lane * 8;
        short8 bh = *(const short8*)fb;
        short8 bl = *(const short8*)(fb + 512);
        short8 ah = ks ? ahi1 : ahi0;
        acc[nt] = __builtin_amdgcn_mfma_f32_16x16x32_bf16(ah, bh, acc[nt], 0, 0, 0);
        acc[nt] = __builtin_amdgcn_mfma_f32_16x16x32_bf16(ah, bl, acc[nt], 0, 0, 0);
      }
    }
#pragma unroll
    for (int nt = 0; nt < 4; ++nt) {
      int feat = nt * 16 + c;
      float s1 = bnp[1][feat], o1 = bnp[2][feat], bb = bnp[0][feat];
#pragma unroll
      for (int r = 0; r < 4; ++r) {
        float y = fmaxf(acc[nt][r] + bb, 0.f);
        tls[wave][q * 4 + r][feat] = fmaf(y, s1, o1);
      }
    }
    float4 u0 = *(const float4*)&tls[wave][c][q * 8];
    float4 u1 = *(const float4*)&tls[wave][c][q * 8 + 4];
    split8(u0, u1, ahi0, alo0);
    u0 = *(const float4*)&tls[wave][c][32 + q * 8];
    u1 = *(const float4*)&tls[wave][c][32 + q * 8 + 4];
    split8(u0, u1, ahi1, alo1);
  }

  // GEMM2: 3-term when A has lo (normal), 2-term in skip1 mode.
  floatx4 acc2[4];
#pragma unroll
  for (int nt = 0; nt < 4; ++nt) acc2[nt] = (floatx4){0.f, 0.f, 0.f, 0.f};
  if (!skip1) {
#pragma unroll
    for (int nt = 0; nt < 4; ++nt) {
#pragma unroll
      for (int ks = 0; ks < 2; ++ks) {
        const ushort* fb = wp2 + ((nt * 2 + ks) * 2) * 512 + lane * 8;
        short8 bh = *(const short8*)fb;
        short8 bl = *(const short8*)(fb + 512);
        short8 ah = ks ? ahi1 : ahi0;
        short8 al = ks ? alo1 : alo0;
        acc2[nt] = __builtin_amdgcn_mfma_f32_16x16x32_bf16(ah, bh, acc2[nt], 0, 0, 0);
        acc2[nt] = __builtin_amdgcn_mfma_f32_16x16x32_bf16(al, bh, acc2[nt], 0, 0, 0);
        acc2[nt] = __builtin_amdgcn_mfma_f32_16x16x32_bf16(ah, bl, acc2[nt], 0, 0, 0);
      }
    }
  } else {
#pragma unroll
    for (int nt = 0; nt < 4; ++nt) {
#pragma unroll
      for (int ks = 0; ks < 2; ++ks) {
        const ushort* fb = wp2 + ((nt * 2 + ks) * 2) * 512 + lane * 8;
        short8 bh = *(const short8*)fb;
        short8 bl = *(const short8*)(fb + 512);
        short8 ah = ks ? ahi1 : ahi0;
        acc2[nt] = __builtin_amdgcn_mfma_f32_16x16x32_bf16(ah, bh, acc2[nt], 0, 0, 0);
        acc2[nt] = __builtin_amdgcn_mfma_f32_16x16x32_bf16(ah, bl, acc2[nt], 0, 0, 0);
      }
    }
  }

  // bn2 -> h bf16 store + LDS stage for pooling
#pragma unroll
  for (int nt = 0; nt < 4; ++nt) {
    int feat = nt * 16 + c;
    float s2 = bnp[4][feat], o2 = bnp[5][feat], bb = bnp[3][feat];
#pragma unroll
    for (int r = 0; r < 4; ++r) {
      int node = base + q * 4 + r;
      int li = wave * 16 + q * 4 + r;
      float val = 0.f;
      if (node < N) {
        float y = fmaxf(acc2[nt][r] + bb, 0.f);
        val = fmaf(y, s2, o2);
        hout[(long)node * 64 + feat] = f2bf(val);
      }
      hls[li][feat] = val;
    }
  }
  __syncthreads();

  // per-graph segment sums over this block's 64 nodes (batch sorted)
  if (tid < 64) {
    int j = tid;
    int nvalid = N - blockbase;
    if (nvalid > 64) nvalid = 64;
    int i = 0;
    while (i < nvalid) {
      int g = batchl[i];
      float s = 0.f;
      while (i < nvalid && batchl[i] == g) { s += hls[i][j]; ++i; }
      atomicAdd(&pooled[(size_t)g * 512 + layer * 64 + j], s);
    }
  }
}

__global__ void z0_kernel(const float* __restrict__ x, const int* __restrict__ rp,
                          const int* __restrict__ col, const float* __restrict__ eps,
                          float* __restrict__ z0, int N) {
  int n = blockIdx.x * blockDim.x + threadIdx.x;
  if (n >= N) return;
  int beg = rp[n], end = rp[n + 1];
  float a = 0.f;
  for (int e = beg; e < end; ++e) a += x[col[e]];
  z0[n] = fmaf(1.0f + eps[0], x[n], a);
}

// layer0 t: bf16 row-major (feeds mfma GEMM2-only mode)
__global__ void t0_kernel(const float* __restrict__ z0, const float* __restrict__ W1f,
                          const float* __restrict__ b1, const float* __restrict__ g1,
                          const float* __restrict__ be1, const float* __restrict__ m1,
                          const float* __restrict__ v1, ushort* __restrict__ t, int N) {
  int idx = blockIdx.x * blockDim.x + threadIdx.x;
  if (idx >= N * 64) return;
  int n = idx >> 6, k = idx & 63;
  float s = g1[k] * rsqrtf(v1[k] + 1e-5f);
  float y = fmaxf(fmaf(z0[n], W1f[k], b1[k]), 0.f);
  t[idx] = f2bf(fmaf(y, s, be1[k] - m1[k] * s));
}

__global__ __launch_bounds__(64) void final_kernel(
    const float* __restrict__ pooled, const int* __restrict__ gs,
    const float* __restrict__ lin1_w, const float* __restrict__ lin1_b,
    const float* __restrict__ lin2_w, const float* __restrict__ lin2_b,
    float* __restrict__ out, int G) {
  int g = blockIdx.x;
  int j = threadIdx.x;
  float inv = 1.0f / fmaxf((float)(gs[g + 1] - gs[g]), 1.0f);
  __shared__ float p[512];
  for (int t = j; t < 512; t += 64) p[t] = pooled[(long)g * 512 + t] * inv;
  __syncthreads();
  float a0 = lin1_b[j], a1 = 0.f, a2 = 0.f, a3 = 0.f;
  for (int k = 0; k < 512; k += 4) {
    a0 = fmaf(p[k + 0], lin1_w[(k + 0) * 64 + j], a0);
    a1 = fmaf(p[k + 1], lin1_w[(k + 1) * 64 + j], a1);
    a2 = fmaf(p[k + 2], lin1_w[(k + 2) * 64 + j], a2);
    a3 = fmaf(p[k + 3], lin1_w[(k + 3) * 64 + j], a3);
  }
  float hv = fmaxf((a0 + a1) + (a2 + a3), 0.f);
  __shared__ float hb[64];
  hb[j] = hv;
  __syncthreads();
  __shared__ float lg[3];
  if (j < 3) {
    float a = lin2_b[j];
#pragma unroll
    for (int k = 0; k < 64; ++k) a = fmaf(hb[k], lin2_w[k * 3 + j], a);
    lg[j] = a;
  }
  __syncthreads();
  if (j < 3) {
    float mx = fmaxf(fmaxf(lg[0], lg[1]), lg[2]);
    float lse = mx + logf(expf(lg[0] - mx) + expf(lg[1] - mx) + expf(lg[2] - mx));
    out[g * 3 + j] = lg[j] - lse;
  }
}

extern "C" void kernel_launch(void* const* d_in, const int* in_sizes, int n_in,
                              void* d_out, int out_size, void* d_ws, size_t ws_size,
                              hipStream_t stream) {
  const float* x        = (const float*)d_in[0];
  const int*   edge     = (const int*)d_in[1];
  const int*   batch    = (const int*)d_in[2];
  const float* eps      = (const float*)d_in[4];
  const float* W1_first = (const float*)d_in[5];
  const float* W1_rest  = (const float*)d_in[6];
  const float* b1       = (const float*)d_in[7];
  const float* g1       = (const float*)d_in[8];
  const float* be1      = (const float*)d_in[9];
  const float* m1       = (const float*)d_in[10];
  const float* v1       = (const float*)d_in[11];
  const float* W2       = (const float*)d_in[12];
  const float* b2       = (const float*)d_in[13];
  const float* g2       = (const float*)d_in[14];
  const float* be2      = (const float*)d_in[15];
  const float* m2       = (const float*)d_in[16];
  const float* v2       = (const float*)d_in[17];
  const float* lin1_w   = (const float*)d_in[18];
  const float* lin1_b   = (const float*)d_in[19];
  const float* lin2_w   = (const float*)d_in[20];
  const float* lin2_b   = (const float*)d_in[21];

  int N = in_sizes[0];
  int E = in_sizes[1] / 2;
  int G = out_size / 3;
  const int* esrc = edge;
  const int* edst = edge + E;
  int NB = (N + (1 << BBITS) - 1) >> BBITS;
  if (NB > 128) NB = 128;

  size_t off = 0;
  auto alloc = [&](size_t bytes) -> char* {
    char* p = (char*)d_ws + off;
    off += (bytes + 255) & ~(size_t)255;
    return p;
  };
  int SB = (N + 255) / 256;
  int*    deg    = (int*)alloc((size_t)N * 4);
  int*    rp     = (int*)alloc((size_t)(N + 1) * 4);
  int*    col    = (int*)alloc((size_t)E * 4);
  int*    bsum   = (int*)alloc((size_t)SB * 4);
  int*    boff   = (int*)alloc((size_t)SB * 4);
  int*    bc     = (int*)alloc((size_t)128 * 16 * 4);
  int*    asrc   = (int*)alloc((size_t)NB * BCAP * 4);
  int*    adst   = (int*)alloc((size_t)NB * BCAP * 4);
  int*    gs     = (int*)alloc((size_t)(G + 1) * 4);
  ushort* wpack  = (ushort*)alloc((size_t)16 * 8192 * 2);
  float*  z0buf  = (float*)alloc((size_t)N * 4);
  ushort* zbuf   = (ushort*)alloc((size_t)N * 64 * 2);
  ushort* hA     = (ushort*)alloc((size_t)N * 64 * 2);
  ushort* hB     = (ushort*)alloc((size_t)N * 64 * 2);
  float*  pooled = (float*)alloc((size_t)G * 512 * 4);
  (void)ws_size;

  // atomic-free binned CSC build
  init_bc_kernel<<<1, 128, 0, stream>>>(bc, NB);
  int ebA = (E + 4095) / 4096;
  bin_edges_kernel<<<ebA, 1024, 0, stream>>>(esrc, edst, bc, asrc, adst, E);
  bucket_count_kernel<<<NB, 1024, 0, stream>>>(adst, bc, deg, N);
  scan_blocksums<<<SB, 256, 0, stream>>>(deg, bsum, N);
  scan_bsum<<<1, 1024, 0, stream>>>(bsum, boff, rp + N, SB);
  scan_final<<<SB, 256, 0, stream>>>(deg, boff, rp, N);
  bucket_scatter_kernel<<<NB, 1024, 0, stream>>>(asrc, adst, bc, rp, col, N);

  graph_bounds_kernel<<<SB, 256, 0, stream>>>(batch, gs, N, G);
  prepack_w_kernel<<<16, 256, 0, stream>>>(W1_rest, W2, wpack);
  (void)hipMemsetAsync(pooled, 0, (size_t)G * 512 * 4, stream);

  int nb = (N + 63) / 64;
  z0_kernel<<<SB, 256, 0, stream>>>(x, rp, col, eps, z0buf, N);
  t0_kernel<<<(N * 64 + 255) / 256, 256, 0, stream>>>(z0buf, W1_first, b1, g1, be1, m1, v1,
                                                      zbuf, N);
  mfma_mlp_kernel<<<nb, 256, 0, stream>>>(zbuf, hA, wpack, wpack + 8192,
      b1, g1, be1, m1, v1, b2, g2, be2, m2, v2, batch, pooled, 0, 1, N);

  ushort* hin = hA;
  ushort* hout = hB;
  for (int i = 1; i < 8; ++i) {
    agg_kernel<<<2048, 256, 0, stream>>>(hin, rp, col, eps, i, zbuf, N);
    mfma_mlp_kernel<<<nb, 256, 0, stream>>>(zbuf, hout,
        wpack + (size_t)(2 * i) * 8192, wpack + (size_t)(2 * i + 1) * 8192,
        b1 + i * 64, g1 + i * 64, be1 + i * 64, m1 + i * 64, v1 + i * 64,
        b2 + i * 64, g2 + i * 64, be2 + i * 64, m2 + i * 64, v2 + i * 64,
        batch, pooled, i, 0, N);
    ushort* t = hin; hin = hout; hout = t;
  }
  final_kernel<<<G, 64, 0, stream>>>(pooled, gs, lin1_w, lin1_b,
                                     lin2_w, lin2_b, (float*)d_out, G);
}

// Round 14
// 713.498 us; speedup vs baseline: 2.8041x; 1.0459x over previous
//
#include <hip/hip_runtime.h>
#include <hip/hip_bf16.h>
#include <math.h>

// ---------------------------------------------------------------------------
// GIN + JumpingKnowledge(cat) + mean-pool + 2-layer head, eval mode.
// R14 (on R13, 746us):
//  - col loads back to CACHED (R13's nt col loads re-fetched each 64B line
//    twice: FETCH 84.7->88.1 MB, dur +3.5us. nt only for single-touch lines).
//  - agg __launch_bounds__(256,8): VGPR=28 allows 32 waves/CU; more
//    outstanding random misses on the latency-bound gather path.
//  - keep: bf16 z + nt z-stores/z-loads (WRITE halved, verified), fused pool,
//    atomic-free CSC build, MFMA MLP.
// ---------------------------------------------------------------------------

typedef unsigned int uint;
typedef unsigned short ushort;
typedef __attribute__((ext_vector_type(8))) short short8;
typedef __attribute__((ext_vector_type(4))) float floatx4;
typedef __attribute__((ext_vector_type(4))) uint uintx4;

#define BBITS 10                 // 1024 nodes per bucket
#define BCAP 20480               // arena capacity per bucket

__device__ __forceinline__ float bf_lo(uint w) { return __uint_as_float(w << 16); }
__device__ __forceinline__ float bf_hi(uint w) { return __uint_as_float(w & 0xffff0000u); }

__device__ __forceinline__ ushort f2bf(float x) {
  __hip_bfloat16 h = __float2bfloat16(x);
  return *(ushort*)&h;
}
__device__ __forceinline__ float bf2f(ushort u) { return __uint_as_float((uint)u << 16); }

__device__ __forceinline__ uint pack_bf16(float a, float b) {
  return (uint)f2bf(a) | ((uint)f2bf(b) << 16);
}

// split 16 fp32 (two 8-chunks) into hi/lo bf16 fragments (used for t in GEMM2)
__device__ __forceinline__ void split8(float4 u0, float4 u1, short8& hi, short8& lo) {
  float v0 = u0.x, v1 = u0.y, v2 = u0.z, v3 = u0.w;
  float v4 = u1.x, v5 = u1.y, v6 = u1.z, v7 = u1.w;
  ushort h0 = f2bf(v0), h1 = f2bf(v1), h2 = f2bf(v2), h3 = f2bf(v3);
  ushort h4 = f2bf(v4), h5 = f2bf(v5), h6 = f2bf(v6), h7 = f2bf(v7);
  hi[0] = (short)h0; hi[1] = (short)h1; hi[2] = (short)h2; hi[3] = (short)h3;
  hi[4] = (short)h4; hi[5] = (short)h5; hi[6] = (short)h6; hi[7] = (short)h7;
  lo[0] = (short)f2bf(v0 - bf2f(h0)); lo[1] = (short)f2bf(v1 - bf2f(h1));
  lo[2] = (short)f2bf(v2 - bf2f(h2)); lo[3] = (short)f2bf(v3 - bf2f(h3));
  lo[4] = (short)f2bf(v4 - bf2f(h4)); lo[5] = (short)f2bf(v5 - bf2f(h5));
  lo[6] = (short)f2bf(v6 - bf2f(h6)); lo[7] = (short)f2bf(v7 - bf2f(h7));
}

// ---- atomic-free binned CSC build -----------------------------------------

__global__ void init_bc_kernel(int* __restrict__ bc, int NB) {
  int b = threadIdx.x;
  if (b < NB) bc[b * 16] = b * BCAP;
}

__global__ __launch_bounds__(1024) void bin_edges_kernel(
    const int* __restrict__ src, const int* __restrict__ dst, int* __restrict__ bc,
    int* __restrict__ arena_src, int* __restrict__ arena_dst, int E) {
  __shared__ int cnt[128], base[128];
  for (long chunk = (long)blockIdx.x * 4096; chunk < E; chunk += (long)gridDim.x * 4096) {
    if (threadIdx.x < 128) cnt[threadIdx.x] = 0;
    __syncthreads();
    int s[4], d[4], b[4], r[4];
#pragma unroll
    for (int u = 0; u < 4; ++u) {
      long e = chunk + threadIdx.x + u * 1024;
      if (e < E) {
        s[u] = src[e];
        d[u] = dst[e];
        b[u] = d[u] >> BBITS;
        r[u] = atomicAdd(&cnt[b[u]], 1);
      }
    }
    __syncthreads();
    if (threadIdx.x < 128)
      base[threadIdx.x] = cnt[threadIdx.x] ? atomicAdd(&bc[threadIdx.x * 16], cnt[threadIdx.x]) : 0;
    __syncthreads();
#pragma unroll
    for (int u = 0; u < 4; ++u) {
      long e = chunk + threadIdx.x + u * 1024;
      if (e < E) {
        int pos = base[b[u]] + r[u];
        arena_src[pos] = s[u];
        arena_dst[pos] = d[u];
      }
    }
    __syncthreads();
  }
}

__global__ __launch_bounds__(1024) void bucket_count_kernel(
    const int* __restrict__ arena_dst, const int* __restrict__ bc,
    int* __restrict__ deg, int N) {
  __shared__ int hist[1 << BBITS];
  int b = blockIdx.x;
  int lo = b << BBITS;
  int hi = min(lo + (1 << BBITS), N);
  hist[threadIdx.x] = 0;
  __syncthreads();
  int cnt = bc[b * 16] - b * BCAP;
  const int* ad = arena_dst + (size_t)b * BCAP;
  for (int i = threadIdx.x; i < cnt; i += 1024) atomicAdd(&hist[ad[i] - lo], 1);
  __syncthreads();
  if (lo + (int)threadIdx.x < hi) deg[lo + threadIdx.x] = hist[threadIdx.x];
}

__global__ __launch_bounds__(1024) void bucket_scatter_kernel(
    const int* __restrict__ arena_src, const int* __restrict__ arena_dst,
    const int* __restrict__ bc, const int* __restrict__ rp,
    int* __restrict__ col, int N) {
  __shared__ int cur[1 << BBITS];
  int b = blockIdx.x;
  int lo = b << BBITS;
  int hi = min(lo + (1 << BBITS), N);
  if (lo + (int)threadIdx.x < hi) cur[threadIdx.x] = rp[lo + threadIdx.x];
  __syncthreads();
  int cnt = bc[b * 16] - b * BCAP;
  const int* ad = arena_dst + (size_t)b * BCAP;
  const int* as = arena_src + (size_t)b * BCAP;
  for (int i = threadIdx.x; i < cnt; i += 1024) {
    int d = ad[i];
    int pos = atomicAdd(&cur[d - lo], 1);
    col[pos] = as[i];
  }
}

// ---- scan -----------------------------------------------------------------
__global__ void scan_blocksums(const int* __restrict__ deg, int* __restrict__ bsum, int N) {
  __shared__ int red[256];
  int i = blockIdx.x * 256 + threadIdx.x;
  red[threadIdx.x] = (i < N) ? deg[i] : 0;
  __syncthreads();
  for (int off = 128; off > 0; off >>= 1) {
    if (threadIdx.x < off) red[threadIdx.x] += red[threadIdx.x + off];
    __syncthreads();
  }
  if (threadIdx.x == 0) bsum[blockIdx.x] = red[0];
}

__global__ void scan_bsum(const int* __restrict__ bsum, int* __restrict__ boff,
                          int* __restrict__ rp_last, int B) {
  __shared__ int tmp[1024];
  int t = threadIdx.x;
  int v = (t < B) ? bsum[t] : 0;
  tmp[t] = v;
  __syncthreads();
  for (int off = 1; off < 1024; off <<= 1) {
    int u = (t >= off) ? tmp[t - off] : 0;
    __syncthreads();
    tmp[t] += u;
    __syncthreads();
  }
  if (t < B) boff[t] = tmp[t] - v;
  if (t == 1023) *rp_last = tmp[1023];
}

__global__ void scan_final(const int* __restrict__ deg, const int* __restrict__ boff,
                           int* __restrict__ rp, int N) {
  __shared__ int tmp[256];
  int i = blockIdx.x * 256 + threadIdx.x;
  int v = (i < N) ? deg[i] : 0;
  tmp[threadIdx.x] = v;
  __syncthreads();
  for (int off = 1; off < 256; off <<= 1) {
    int u = (threadIdx.x >= off) ? tmp[threadIdx.x - off] : 0;
    __syncthreads();
    tmp[threadIdx.x] += u;
    __syncthreads();
  }
  if (i < N) rp[i] = boff[blockIdx.x] + tmp[threadIdx.x] - v;
}

__global__ void graph_bounds_kernel(const int* __restrict__ batch, int* __restrict__ gs,
                                    int N, int G) {
  int n = blockIdx.x * 256 + threadIdx.x;
  if (n >= N) return;
  int b = batch[n];
  int bp = (n == 0) ? -1 : batch[n - 1];
  for (int g = bp + 1; g <= b; ++g) gs[g] = n;
  if (n == N - 1)
    for (int g = b + 1; g <= G; ++g) gs[g] = N;
}

// Prepack W1/W2 into MFMA B-fragment order, split hi/lo bf16.
__global__ void prepack_w_kernel(const float* __restrict__ W1_rest,
                                 const float* __restrict__ W2, ushort* __restrict__ wp) {
  int l = blockIdx.x >> 1, g = blockIdx.x & 1;
  const float* W;
  if (g == 0) {
    if (l == 0) return;
    W = W1_rest + (size_t)(l - 1) * 4096;
  } else {
    W = W2 + (size_t)l * 4096;
  }
  ushort* out = wp + (size_t)(l * 2 + g) * 8192;
  for (int idx = threadIdx.x; idx < 4096; idx += blockDim.x) {
    int j = idx & 7, lane = (idx >> 3) & 63, ks = (idx >> 9) & 1, nt = (idx >> 10) & 3;
    int k = ks * 32 + (lane >> 4) * 8 + j;
    int n = nt * 16 + (lane & 15);
    float w = W[k * 64 + n];
    ushort hi = f2bf(w);
    ushort lo = f2bf(w - bf2f(hi));
    size_t base = (size_t)((nt * 2 + ks) * 2) * 512 + lane * 8 + j;
    out[base] = hi;
    out[base + 512] = lo;
  }
}

// z[n][:] = (1+eps_l)*h[n][:] + sum_e h[col[e]][:]   (h bf16, z bf16 out)
// col loads cached (R13 nt regression); z stores nt (single-touch stream).
__global__ __launch_bounds__(256, 8) void agg_kernel(
    const ushort* __restrict__ hb, const int* __restrict__ rp,
    const int* __restrict__ col, const float* __restrict__ eps,
    int layer, ushort* __restrict__ zb, int N) {
  int lane = threadIdx.x & 63;
  int g = lane >> 3;
  int r = lane & 7;
  int wave = blockIdx.x * (blockDim.x >> 6) + (threadIdx.x >> 6);
  int nwaves = gridDim.x * (blockDim.x >> 6);
  float ep = 1.0f + eps[layer];
  for (int n = wave * 2; n < N; n += nwaves * 2) {
    int n0 = __builtin_amdgcn_readfirstlane(n);
    int n1 = n0 + 1;
    int beg0 = rp[n0];
    int end0 = rp[n0 + 1];
    int end1 = (n1 < N) ? rp[n1 + 1] : end0;
    float a0[8] = {0.f, 0.f, 0.f, 0.f, 0.f, 0.f, 0.f, 0.f};
    float a1[8] = {0.f, 0.f, 0.f, 0.f, 0.f, 0.f, 0.f, 0.f};
    float b0[8] = {0.f, 0.f, 0.f, 0.f, 0.f, 0.f, 0.f, 0.f};
    float b1v[8] = {0.f, 0.f, 0.f, 0.f, 0.f, 0.f, 0.f, 0.f};
    int e0 = beg0 + g;
    int e1 = end0 + g;
    while (e0 < end0 || e1 < end1) {
      if (e0 < end0) {
        int s = col[e0];
        uint4 w = ((const uint4*)(hb + (long)s * 64))[r];
        a0[0] += bf_lo(w.x); a0[1] += bf_hi(w.x);
        a0[2] += bf_lo(w.y); a0[3] += bf_hi(w.y);
        a0[4] += bf_lo(w.z); a0[5] += bf_hi(w.z);
        a0[6] += bf_lo(w.w); a0[7] += bf_hi(w.w);
      }
      if (e0 + 8 < end0) {
        int s = col[e0 + 8];
        uint4 w = ((const uint4*)(hb + (long)s * 64))[r];
        a1[0] += bf_lo(w.x); a1[1] += bf_hi(w.x);
        a1[2] += bf_lo(w.y); a1[3] += bf_hi(w.y);
        a1[4] += bf_lo(w.z); a1[5] += bf_hi(w.z);
        a1[6] += bf_lo(w.w); a1[7] += bf_hi(w.w);
      }
      if (e1 < end1) {
        int s = col[e1];
        uint4 w = ((const uint4*)(hb + (long)s * 64))[r];
        b0[0] += bf_lo(w.x); b0[1] += bf_hi(w.x);
        b0[2] += bf_lo(w.y); b0[3] += bf_hi(w.y);
        b0[4] += bf_lo(w.z); b0[5] += bf_hi(w.z);
        b0[6] += bf_lo(w.w); b0[7] += bf_hi(w.w);
      }
      if (e1 + 8 < end1) {
        int s = col[e1 + 8];
        uint4 w = ((const uint4*)(hb + (long)s * 64))[r];
        b1v[0] += bf_lo(w.x); b1v[1] += bf_hi(w.x);
        b1v[2] += bf_lo(w.y); b1v[3] += bf_hi(w.y);
        b1v[4] += bf_lo(w.z); b1v[5] += bf_hi(w.z);
        b1v[6] += bf_lo(w.w); b1v[7] += bf_hi(w.w);
      }
      e0 += 16; e1 += 16;
    }
#pragma unroll
    for (int j = 0; j < 8; ++j) { a0[j] += a1[j]; b0[j] += b1v[j]; }
#pragma unroll
    for (int m = 8; m <= 32; m <<= 1) {
#pragma unroll
      for (int j = 0; j < 8; ++j) {
        a0[j] += __shfl_xor(a0[j], m, 64);
        b0[j] += __shfl_xor(b0[j], m, 64);
      }
    }
    if (g == 0) {
      uint4 hv = ((const uint4*)(hb + (long)n0 * 64))[r];
      float v0 = fmaf(ep, bf_lo(hv.x), a0[0]), v1 = fmaf(ep, bf_hi(hv.x), a0[1]);
      float v2 = fmaf(ep, bf_lo(hv.y), a0[2]), v3 = fmaf(ep, bf_hi(hv.y), a0[3]);
      float v4 = fmaf(ep, bf_lo(hv.z), a0[4]), v5 = fmaf(ep, bf_hi(hv.z), a0[5]);
      float v6 = fmaf(ep, bf_lo(hv.w), a0[6]), v7 = fmaf(ep, bf_hi(hv.w), a0[7]);
      uintx4 w;
      w.x = pack_bf16(v0, v1); w.y = pack_bf16(v2, v3);
      w.z = pack_bf16(v4, v5); w.w = pack_bf16(v6, v7);
      __builtin_nontemporal_store(w, (uintx4*)(zb + (size_t)n0 * 64 + r * 8));
    } else if (g == 1 && n1 < N) {
      uint4 hv = ((const uint4*)(hb + (long)n1 * 64))[r];
      float v0 = fmaf(ep, bf_lo(hv.x), b0[0]), v1 = fmaf(ep, bf_hi(hv.x), b0[1]);
      float v2 = fmaf(ep, bf_lo(hv.y), b0[2]), v3 = fmaf(ep, bf_hi(hv.y), b0[3]);
      float v4 = fmaf(ep, bf_lo(hv.z), b0[4]), v5 = fmaf(ep, bf_hi(hv.z), b0[5]);
      float v6 = fmaf(ep, bf_lo(hv.w), b0[6]), v7 = fmaf(ep, bf_hi(hv.w), b0[7]);
      uintx4 w;
      w.x = pack_bf16(v0, v1); w.y = pack_bf16(v2, v3);
      w.z = pack_bf16(v4, v5); w.w = pack_bf16(v6, v7);
      __builtin_nontemporal_store(w, (uintx4*)(zb + (size_t)n1 * 64 + r * 8));
    }
  }
}

// ---------------------------------------------------------------------------
// MFMA MLP + fused mean-pool partial sums.
// ---------------------------------------------------------------------------
__global__ __launch_bounds__(256) void mfma_mlp_kernel(
    const ushort* __restrict__ zb, ushort* __restrict__ hout,
    const ushort* __restrict__ wp1, const ushort* __restrict__ wp2,
    const float* __restrict__ b1, const float* __restrict__ g1,
    const float* __restrict__ be1, const float* __restrict__ m1,
    const float* __restrict__ v1,
    const float* __restrict__ b2, const float* __restrict__ g2,
    const float* __restrict__ be2, const float* __restrict__ m2,
    const float* __restrict__ v2,
    const int* __restrict__ batch, float* __restrict__ pooled,
    int layer, int skip1, int N) {
  __shared__ float bnp[6][64];
  __shared__ float tls[4][16][68];
  __shared__ float hls[64][68];
  __shared__ int batchl[64];
  int tid = threadIdx.x;
  int blockbase = blockIdx.x * 64;
  if (tid < 64) {
    bnp[0][tid] = b1[tid];
    float s1 = g1[tid] * rsqrtf(v1[tid] + 1e-5f);
    bnp[1][tid] = s1;
    bnp[2][tid] = be1[tid] - m1[tid] * s1;
    bnp[3][tid] = b2[tid];
    float s2 = g2[tid] * rsqrtf(v2[tid] + 1e-5f);
    bnp[4][tid] = s2;
    bnp[5][tid] = be2[tid] - m2[tid] * s2;
    batchl[tid] = (blockbase + tid < N) ? batch[blockbase + tid] : -1;
  }
  __syncthreads();
  int wave = tid >> 6, lane = tid & 63;
  int q = lane >> 4, c = lane & 15;
  int base = blockbase + wave * 16;

  // A fragments from global bf16 z (nontemporal: single-use stream)
  short8 ahi0, alo0, ahi1, alo1;
  {
    long row = base + c;
    if (row >= N) row = N - 1;
    const ushort* zr = zb + row * 64;
    ahi0 = __builtin_nontemporal_load((const short8*)(zr + q * 8));
    ahi1 = __builtin_nontemporal_load((const short8*)(zr + 32 + q * 8));
  }

  if (!skip1) {
    floatx4 acc[4];
#pragma unroll
    for (int nt = 0; nt < 4; ++nt) acc[nt] = (floatx4){0.f, 0.f, 0.f, 0.f};
#pragma unroll
    for (int nt = 0; nt < 4; ++nt) {
#pragma unroll
      for (int ks = 0; ks < 2; ++ks) {
        const ushort* fb = wp1 + ((nt * 2 + ks) * 2) * 512 + lane * 8;
        short8 bh = *(const short8*)fb;
        short8 bl = *(const short8*)(fb + 512);
        short8 ah = ks ? ahi1 : ahi0;
        acc[nt] = __builtin_amdgcn_mfma_f32_16x16x32_bf16(ah, bh, acc[nt], 0, 0, 0);
        acc[nt] = __builtin_amdgcn_mfma_f32_16x16x32_bf16(ah, bl, acc[nt], 0, 0, 0);
      }
    }
#pragma unroll
    for (int nt = 0; nt < 4; ++nt) {
      int feat = nt * 16 + c;
      float s1 = bnp[1][feat], o1 = bnp[2][feat], bb = bnp[0][feat];
#pragma unroll
      for (int r = 0; r < 4; ++r) {
        float y = fmaxf(acc[nt][r] + bb, 0.f);
        tls[wave][q * 4 + r][feat] = fmaf(y, s1, o1);
      }
    }
    float4 u0 = *(const float4*)&tls[wave][c][q * 8];
    float4 u1 = *(const float4*)&tls[wave][c][q * 8 + 4];
    split8(u0, u1, ahi0, alo0);
    u0 = *(const float4*)&tls[wave][c][32 + q * 8];
    u1 = *(const float4*)&tls[wave][c][32 + q * 8 + 4];
    split8(u0, u1, ahi1, alo1);
  }

  // GEMM2: 3-term when A has lo (normal), 2-term in skip1 mode.
  floatx4 acc2[4];
#pragma unroll
  for (int nt = 0; nt < 4; ++nt) acc2[nt] = (floatx4){0.f, 0.f, 0.f, 0.f};
  if (!skip1) {
#pragma unroll
    for (int nt = 0; nt < 4; ++nt) {
#pragma unroll
      for (int ks = 0; ks < 2; ++ks) {
        const ushort* fb = wp2 + ((nt * 2 + ks) * 2) * 512 + lane * 8;
        short8 bh = *(const short8*)fb;
        short8 bl = *(const short8*)(fb + 512);
        short8 ah = ks ? ahi1 : ahi0;
        short8 al = ks ? alo1 : alo0;
        acc2[nt] = __builtin_amdgcn_mfma_f32_16x16x32_bf16(ah, bh, acc2[nt], 0, 0, 0);
        acc2[nt] = __builtin_amdgcn_mfma_f32_16x16x32_bf16(al, bh, acc2[nt], 0, 0, 0);
        acc2[nt] = __builtin_amdgcn_mfma_f32_16x16x32_bf16(ah, bl, acc2[nt], 0, 0, 0);
      }
    }
  } else {
#pragma unroll
    for (int nt = 0; nt < 4; ++nt) {
#pragma unroll
      for (int ks = 0; ks < 2; ++ks) {
        const ushort* fb = wp2 + ((nt * 2 + ks) * 2) * 512 + lane * 8;
        short8 bh = *(const short8*)fb;
        short8 bl = *(const short8*)(fb + 512);
        short8 ah = ks ? ahi1 : ahi0;
        acc2[nt] = __builtin_amdgcn_mfma_f32_16x16x32_bf16(ah, bh, acc2[nt], 0, 0, 0);
        acc2[nt] = __builtin_amdgcn_mfma_f32_16x16x32_bf16(ah, bl, acc2[nt], 0, 0, 0);
      }
    }
  }

  // bn2 -> h bf16 store + LDS stage for pooling
#pragma unroll
  for (int nt = 0; nt < 4; ++nt) {
    int feat = nt * 16 + c;
    float s2 = bnp[4][feat], o2 = bnp[5][feat], bb = bnp[3][feat];
#pragma unroll
    for (int r = 0; r < 4; ++r) {
      int node = base + q * 4 + r;
      int li = wave * 16 + q * 4 + r;
      float val = 0.f;
      if (node < N) {
        float y = fmaxf(acc2[nt][r] + bb, 0.f);
        val = fmaf(y, s2, o2);
        hout[(long)node * 64 + feat] = f2bf(val);
      }
      hls[li][feat] = val;
    }
  }
  __syncthreads();

  // per-graph segment sums over this block's 64 nodes (batch sorted)
  if (tid < 64) {
    int j = tid;
    int nvalid = N - blockbase;
    if (nvalid > 64) nvalid = 64;
    int i = 0;
    while (i < nvalid) {
      int g = batchl[i];
      float s = 0.f;
      while (i < nvalid && batchl[i] == g) { s += hls[i][j]; ++i; }
      atomicAdd(&pooled[(size_t)g * 512 + layer * 64 + j], s);
    }
  }
}

__global__ void z0_kernel(const float* __restrict__ x, const int* __restrict__ rp,
                          const int* __restrict__ col, const float* __restrict__ eps,
                          float* __restrict__ z0, int N) {
  int n = blockIdx.x * blockDim.x + threadIdx.x;
  if (n >= N) return;
  int beg = rp[n], end = rp[n + 1];
  float a = 0.f;
  for (int e = beg; e < end; ++e) a += x[col[e]];
  z0[n] = fmaf(1.0f + eps[0], x[n], a);
}

// layer0 t: bf16 row-major (feeds mfma GEMM2-only mode)
__global__ void t0_kernel(const float* __restrict__ z0, const float* __restrict__ W1f,
                          const float* __restrict__ b1, const float* __restrict__ g1,
                          const float* __restrict__ be1, const float* __restrict__ m1,
                          const float* __restrict__ v1, ushort* __restrict__ t, int N) {
  int idx = blockIdx.x * blockDim.x + threadIdx.x;
  if (idx >= N * 64) return;
  int n = idx >> 6, k = idx & 63;
  float s = g1[k] * rsqrtf(v1[k] + 1e-5f);
  float y = fmaxf(fmaf(z0[n], W1f[k], b1[k]), 0.f);
  t[idx] = f2bf(fmaf(y, s, be1[k] - m1[k] * s));
}

__global__ __launch_bounds__(64) void final_kernel(
    const float* __restrict__ pooled, const int* __restrict__ gs,
    const float* __restrict__ lin1_w, const float* __restrict__ lin1_b,
    const float* __restrict__ lin2_w, const float* __restrict__ lin2_b,
    float* __restrict__ out, int G) {
  int g = blockIdx.x;
  int j = threadIdx.x;
  float inv = 1.0f / fmaxf((float)(gs[g + 1] - gs[g]), 1.0f);
  __shared__ float p[512];
  for (int t = j; t < 512; t += 64) p[t] = pooled[(long)g * 512 + t] * inv;
  __syncthreads();
  float a0 = lin1_b[j], a1 = 0.f, a2 = 0.f, a3 = 0.f;
  for (int k = 0; k < 512; k += 4) {
    a0 = fmaf(p[k + 0], lin1_w[(k + 0) * 64 + j], a0);
    a1 = fmaf(p[k + 1], lin1_w[(k + 1) * 64 + j], a1);
    a2 = fmaf(p[k + 2], lin1_w[(k + 2) * 64 + j], a2);
    a3 = fmaf(p[k + 3], lin1_w[(k + 3) * 64 + j], a3);
  }
  float hv = fmaxf((a0 + a1) + (a2 + a3), 0.f);
  __shared__ float hb[64];
  hb[j] = hv;
  __syncthreads();
  __shared__ float lg[3];
  if (j < 3) {
    float a = lin2_b[j];
#pragma unroll
    for (int k = 0; k < 64; ++k) a = fmaf(hb[k], lin2_w[k * 3 + j], a);
    lg[j] = a;
  }
  __syncthreads();
  if (j < 3) {
    float mx = fmaxf(fmaxf(lg[0], lg[1]), lg[2]);
    float lse = mx + logf(expf(lg[0] - mx) + expf(lg[1] - mx) + expf(lg[2] - mx));
    out[g * 3 + j] = lg[j] - lse;
  }
}

extern "C" void kernel_launch(void* const* d_in, const int* in_sizes, int n_in,
                              void* d_out, int out_size, void* d_ws, size_t ws_size,
                              hipStream_t stream) {
  const float* x        = (const float*)d_in[0];
  const int*   edge     = (const int*)d_in[1];
  const int*   batch    = (const int*)d_in[2];
  const float* eps      = (const float*)d_in[4];
  const float* W1_first = (const float*)d_in[5];
  const float* W1_rest  = (const float*)d_in[6];
  const float* b1       = (const float*)d_in[7];
  const float* g1       = (const float*)d_in[8];
  const float* be1      = (const float*)d_in[9];
  const float* m1       = (const float*)d_in[10];
  const float* v1       = (const float*)d_in[11];
  const float* W2       = (const float*)d_in[12];
  const float* b2       = (const float*)d_in[13];
  const float* g2       = (const float*)d_in[14];
  const float* be2      = (const float*)d_in[15];
  const float* m2       = (const float*)d_in[16];
  const float* v2       = (const float*)d_in[17];
  const float* lin1_w   = (const float*)d_in[18];
  const float* lin1_b   = (const float*)d_in[19];
  const float* lin2_w   = (const float*)d_in[20];
  const float* lin2_b   = (const float*)d_in[21];

  int N = in_sizes[0];
  int E = in_sizes[1] / 2;
  int G = out_size / 3;
  const int* esrc = edge;
  const int* edst = edge + E;
  int NB = (N + (1 << BBITS) - 1) >> BBITS;
  if (NB > 128) NB = 128;

  size_t off = 0;
  auto alloc = [&](size_t bytes) -> char* {
    char* p = (char*)d_ws + off;
    off += (bytes + 255) & ~(size_t)255;
    return p;
  };
  int SB = (N + 255) / 256;
  int*    deg    = (int*)alloc((size_t)N * 4);
  int*    rp     = (int*)alloc((size_t)(N + 1) * 4);
  int*    col    = (int*)alloc((size_t)E * 4);
  int*    bsum   = (int*)alloc((size_t)SB * 4);
  int*    boff   = (int*)alloc((size_t)SB * 4);
  int*    bc     = (int*)alloc((size_t)128 * 16 * 4);
  int*    asrc   = (int*)alloc((size_t)NB * BCAP * 4);
  int*    adst   = (int*)alloc((size_t)NB * BCAP * 4);
  int*    gs     = (int*)alloc((size_t)(G + 1) * 4);
  ushort* wpack  = (ushort*)alloc((size_t)16 * 8192 * 2);
  float*  z0buf  = (float*)alloc((size_t)N * 4);
  ushort* zbuf   = (ushort*)alloc((size_t)N * 64 * 2);
  ushort* hA     = (ushort*)alloc((size_t)N * 64 * 2);
  ushort* hB     = (ushort*)alloc((size_t)N * 64 * 2);
  float*  pooled = (float*)alloc((size_t)G * 512 * 4);
  (void)ws_size;

  // atomic-free binned CSC build
  init_bc_kernel<<<1, 128, 0, stream>>>(bc, NB);
  int ebA = (E + 4095) / 4096;
  bin_edges_kernel<<<ebA, 1024, 0, stream>>>(esrc, edst, bc, asrc, adst, E);
  bucket_count_kernel<<<NB, 1024, 0, stream>>>(adst, bc, deg, N);
  scan_blocksums<<<SB, 256, 0, stream>>>(deg, bsum, N);
  scan_bsum<<<1, 1024, 0, stream>>>(bsum, boff, rp + N, SB);
  scan_final<<<SB, 256, 0, stream>>>(deg, boff, rp, N);
  bucket_scatter_kernel<<<NB, 1024, 0, stream>>>(asrc, adst, bc, rp, col, N);

  graph_bounds_kernel<<<SB, 256, 0, stream>>>(batch, gs, N, G);
  prepack_w_kernel<<<16, 256, 0, stream>>>(W1_rest, W2, wpack);
  (void)hipMemsetAsync(pooled, 0, (size_t)G * 512 * 4, stream);

  int nb = (N + 63) / 64;
  z0_kernel<<<SB, 256, 0, stream>>>(x, rp, col, eps, z0buf, N);
  t0_kernel<<<(N * 64 + 255) / 256, 256, 0, stream>>>(z0buf, W1_first, b1, g1, be1, m1, v1,
                                                      zbuf, N);
  mfma_mlp_kernel<<<nb, 256, 0, stream>>>(zbuf, hA, wpack, wpack + 8192,
      b1, g1, be1, m1, v1, b2, g2, be2, m2, v2, batch, pooled, 0, 1, N);

  ushort* hin = hA;
  ushort* hout = hB;
  for (int i = 1; i < 8; ++i) {
    agg_kernel<<<2048, 256, 0, stream>>>(hin, rp, col, eps, i, zbuf, N);
    mfma_mlp_kernel<<<nb, 256, 0, stream>>>(zbuf, hout,
        wpack + (size_t)(2 * i) * 8192, wpack + (size_t)(2 * i + 1) * 8192,
        b1 + i * 64, g1 + i * 64, be1 + i * 64, m1 + i * 64, v1 + i * 64,
        b2 + i * 64, g2 + i * 64, be2 + i * 64, m2 + i * 64, v2 + i * 64,
        batch, pooled, i, 0, N);
    ushort* t = hin; hin = hout; hout = t;
  }
  final_kernel<<<G, 64, 0, stream>>>(pooled, gs, lin1_w, lin1_b,
                                     lin2_w, lin2_b, (float*)d_out, G);
}

// Round 15
// 641.217 us; speedup vs baseline: 3.1202x; 1.1127x over previous
//
#include <hip/hip_runtime.h>
#include <hip/hip_bf16.h>
#include <math.h>

// ---------------------------------------------------------------------------
// GIN + JumpingKnowledge(cat) + mean-pool + 2-layer head, eval mode.
// R15 (on R14, 713us):
//  - arena packed to 1 uint/edge ((src<<10)|dlocal): bin writes & scatter
//    reads halved.
//  - t0 fused into mfma_mlp skip1 (A-frags computed from z0+W1f+bn1 in-kernel,
//    fp32 -> hi/lo 3-term): t0 dispatch + 25.6MB round-trip removed.
//  - tls/hls LDS unioned (36.6 -> 19.2 KB, 8 blocks/CU).
// Keeps: R14 agg (cached col, (256,8), nt z-stores), bf16 z, fused pool,
// atomic-free CSC build, split-bf16 MFMA MLP.
// ---------------------------------------------------------------------------

typedef unsigned int uint;
typedef unsigned short ushort;
typedef __attribute__((ext_vector_type(8))) short short8;
typedef __attribute__((ext_vector_type(4))) float floatx4;
typedef __attribute__((ext_vector_type(4))) uint uintx4;

#define BBITS 10                 // 1024 nodes per bucket
#define BCAP 20480               // arena capacity per bucket
#define BMASK ((1 << BBITS) - 1)

__device__ __forceinline__ float bf_lo(uint w) { return __uint_as_float(w << 16); }
__device__ __forceinline__ float bf_hi(uint w) { return __uint_as_float(w & 0xffff0000u); }

__device__ __forceinline__ ushort f2bf(float x) {
  __hip_bfloat16 h = __float2bfloat16(x);
  return *(ushort*)&h;
}
__device__ __forceinline__ float bf2f(ushort u) { return __uint_as_float((uint)u << 16); }

__device__ __forceinline__ uint pack_bf16(float a, float b) {
  return (uint)f2bf(a) | ((uint)f2bf(b) << 16);
}

__device__ __forceinline__ void split8(float4 u0, float4 u1, short8& hi, short8& lo) {
  float v0 = u0.x, v1 = u0.y, v2 = u0.z, v3 = u0.w;
  float v4 = u1.x, v5 = u1.y, v6 = u1.z, v7 = u1.w;
  ushort h0 = f2bf(v0), h1 = f2bf(v1), h2 = f2bf(v2), h3 = f2bf(v3);
  ushort h4 = f2bf(v4), h5 = f2bf(v5), h6 = f2bf(v6), h7 = f2bf(v7);
  hi[0] = (short)h0; hi[1] = (short)h1; hi[2] = (short)h2; hi[3] = (short)h3;
  hi[4] = (short)h4; hi[5] = (short)h5; hi[6] = (short)h6; hi[7] = (short)h7;
  lo[0] = (short)f2bf(v0 - bf2f(h0)); lo[1] = (short)f2bf(v1 - bf2f(h1));
  lo[2] = (short)f2bf(v2 - bf2f(h2)); lo[3] = (short)f2bf(v3 - bf2f(h3));
  lo[4] = (short)f2bf(v4 - bf2f(h4)); lo[5] = (short)f2bf(v5 - bf2f(h5));
  lo[6] = (short)f2bf(v6 - bf2f(h6)); lo[7] = (short)f2bf(v7 - bf2f(h7));
}

// ---- atomic-free binned CSC build (packed arena) ---------------------------

__global__ void init_bc_kernel(int* __restrict__ bc, int NB) {
  int b = threadIdx.x;
  if (b < NB) bc[b * 16] = b * BCAP;
}

__global__ __launch_bounds__(1024) void bin_edges_kernel(
    const int* __restrict__ src, const int* __restrict__ dst, int* __restrict__ bc,
    uint* __restrict__ arena, int E) {
  __shared__ int cnt[128], base[128];
  for (long chunk = (long)blockIdx.x * 4096; chunk < E; chunk += (long)gridDim.x * 4096) {
    if (threadIdx.x < 128) cnt[threadIdx.x] = 0;
    __syncthreads();
    uint v[4];
    int b[4], r[4];
#pragma unroll
    for (int u = 0; u < 4; ++u) {
      long e = chunk + threadIdx.x + u * 1024;
      if (e < E) {
        int s = src[e];
        int d = dst[e];
        b[u] = d >> BBITS;
        v[u] = ((uint)s << BBITS) | (uint)(d & BMASK);
        r[u] = atomicAdd(&cnt[b[u]], 1);
      }
    }
    __syncthreads();
    if (threadIdx.x < 128)
      base[threadIdx.x] = cnt[threadIdx.x] ? atomicAdd(&bc[threadIdx.x * 16], cnt[threadIdx.x]) : 0;
    __syncthreads();
#pragma unroll
    for (int u = 0; u < 4; ++u) {
      long e = chunk + threadIdx.x + u * 1024;
      if (e < E) arena[base[b[u]] + r[u]] = v[u];
    }
    __syncthreads();
  }
}

__global__ __launch_bounds__(1024) void bucket_count_kernel(
    const uint* __restrict__ arena, const int* __restrict__ bc,
    int* __restrict__ deg, int N) {
  __shared__ int hist[1 << BBITS];
  int b = blockIdx.x;
  int lo = b << BBITS;
  int hi = min(lo + (1 << BBITS), N);
  hist[threadIdx.x] = 0;
  __syncthreads();
  int cnt = bc[b * 16] - b * BCAP;
  const uint* ad = arena + (size_t)b * BCAP;
  for (int i = threadIdx.x; i < cnt; i += 1024) atomicAdd(&hist[ad[i] & BMASK], 1);
  __syncthreads();
  if (lo + (int)threadIdx.x < hi) deg[lo + threadIdx.x] = hist[threadIdx.x];
}

__global__ __launch_bounds__(1024) void bucket_scatter_kernel(
    const uint* __restrict__ arena, const int* __restrict__ bc,
    const int* __restrict__ rp, int* __restrict__ col, int N) {
  __shared__ int cur[1 << BBITS];
  int b = blockIdx.x;
  int lo = b << BBITS;
  int hi = min(lo + (1 << BBITS), N);
  if (lo + (int)threadIdx.x < hi) cur[threadIdx.x] = rp[lo + threadIdx.x];
  __syncthreads();
  int cnt = bc[b * 16] - b * BCAP;
  const uint* ad = arena + (size_t)b * BCAP;
  for (int i = threadIdx.x; i < cnt; i += 1024) {
    uint v = ad[i];
    int pos = atomicAdd(&cur[v & BMASK], 1);
    col[pos] = (int)(v >> BBITS);
  }
}

// ---- scan -----------------------------------------------------------------
__global__ void scan_blocksums(const int* __restrict__ deg, int* __restrict__ bsum, int N) {
  __shared__ int red[256];
  int i = blockIdx.x * 256 + threadIdx.x;
  red[threadIdx.x] = (i < N) ? deg[i] : 0;
  __syncthreads();
  for (int off = 128; off > 0; off >>= 1) {
    if (threadIdx.x < off) red[threadIdx.x] += red[threadIdx.x + off];
    __syncthreads();
  }
  if (threadIdx.x == 0) bsum[blockIdx.x] = red[0];
}

__global__ void scan_bsum(const int* __restrict__ bsum, int* __restrict__ boff,
                          int* __restrict__ rp_last, int B) {
  __shared__ int tmp[1024];
  int t = threadIdx.x;
  int v = (t < B) ? bsum[t] : 0;
  tmp[t] = v;
  __syncthreads();
  for (int off = 1; off < 1024; off <<= 1) {
    int u = (t >= off) ? tmp[t - off] : 0;
    __syncthreads();
    tmp[t] += u;
    __syncthreads();
  }
  if (t < B) boff[t] = tmp[t] - v;
  if (t == 1023) *rp_last = tmp[1023];
}

__global__ void scan_final(const int* __restrict__ deg, const int* __restrict__ boff,
                           int* __restrict__ rp, int N) {
  __shared__ int tmp[256];
  int i = blockIdx.x * 256 + threadIdx.x;
  int v = (i < N) ? deg[i] : 0;
  tmp[threadIdx.x] = v;
  __syncthreads();
  for (int off = 1; off < 256; off <<= 1) {
    int u = (threadIdx.x >= off) ? tmp[threadIdx.x - off] : 0;
    __syncthreads();
    tmp[threadIdx.x] += u;
    __syncthreads();
  }
  if (i < N) rp[i] = boff[blockIdx.x] + tmp[threadIdx.x] - v;
}

__global__ void graph_bounds_kernel(const int* __restrict__ batch, int* __restrict__ gs,
                                    int N, int G) {
  int n = blockIdx.x * 256 + threadIdx.x;
  if (n >= N) return;
  int b = batch[n];
  int bp = (n == 0) ? -1 : batch[n - 1];
  for (int g = bp + 1; g <= b; ++g) gs[g] = n;
  if (n == N - 1)
    for (int g = b + 1; g <= G; ++g) gs[g] = N;
}

// Prepack W1/W2 into MFMA B-fragment order, split hi/lo bf16.
__global__ void prepack_w_kernel(const float* __restrict__ W1_rest,
                                 const float* __restrict__ W2, ushort* __restrict__ wp) {
  int l = blockIdx.x >> 1, g = blockIdx.x & 1;
  const float* W;
  if (g == 0) {
    if (l == 0) return;
    W = W1_rest + (size_t)(l - 1) * 4096;
  } else {
    W = W2 + (size_t)l * 4096;
  }
  ushort* out = wp + (size_t)(l * 2 + g) * 8192;
  for (int idx = threadIdx.x; idx < 4096; idx += blockDim.x) {
    int j = idx & 7, lane = (idx >> 3) & 63, ks = (idx >> 9) & 1, nt = (idx >> 10) & 3;
    int k = ks * 32 + (lane >> 4) * 8 + j;
    int n = nt * 16 + (lane & 15);
    float w = W[k * 64 + n];
    ushort hi = f2bf(w);
    ushort lo = f2bf(w - bf2f(hi));
    size_t base = (size_t)((nt * 2 + ks) * 2) * 512 + lane * 8 + j;
    out[base] = hi;
    out[base + 512] = lo;
  }
}

// z[n][:] = (1+eps_l)*h[n][:] + sum_e h[col[e]][:]   (h bf16, z bf16 out)
__global__ __launch_bounds__(256, 8) void agg_kernel(
    const ushort* __restrict__ hb, const int* __restrict__ rp,
    const int* __restrict__ col, const float* __restrict__ eps,
    int layer, ushort* __restrict__ zb, int N) {
  int lane = threadIdx.x & 63;
  int g = lane >> 3;
  int r = lane & 7;
  int wave = blockIdx.x * (blockDim.x >> 6) + (threadIdx.x >> 6);
  int nwaves = gridDim.x * (blockDim.x >> 6);
  float ep = 1.0f + eps[layer];
  for (int n = wave * 2; n < N; n += nwaves * 2) {
    int n0 = __builtin_amdgcn_readfirstlane(n);
    int n1 = n0 + 1;
    int beg0 = rp[n0];
    int end0 = rp[n0 + 1];
    int end1 = (n1 < N) ? rp[n1 + 1] : end0;
    float a0[8] = {0.f, 0.f, 0.f, 0.f, 0.f, 0.f, 0.f, 0.f};
    float a1[8] = {0.f, 0.f, 0.f, 0.f, 0.f, 0.f, 0.f, 0.f};
    float b0[8] = {0.f, 0.f, 0.f, 0.f, 0.f, 0.f, 0.f, 0.f};
    float b1v[8] = {0.f, 0.f, 0.f, 0.f, 0.f, 0.f, 0.f, 0.f};
    int e0 = beg0 + g;
    int e1 = end0 + g;
    while (e0 < end0 || e1 < end1) {
      if (e0 < end0) {
        int s = col[e0];
        uint4 w = ((const uint4*)(hb + (long)s * 64))[r];
        a0[0] += bf_lo(w.x); a0[1] += bf_hi(w.x);
        a0[2] += bf_lo(w.y); a0[3] += bf_hi(w.y);
        a0[4] += bf_lo(w.z); a0[5] += bf_hi(w.z);
        a0[6] += bf_lo(w.w); a0[7] += bf_hi(w.w);
      }
      if (e0 + 8 < end0) {
        int s = col[e0 + 8];
        uint4 w = ((const uint4*)(hb + (long)s * 64))[r];
        a1[0] += bf_lo(w.x); a1[1] += bf_hi(w.x);
        a1[2] += bf_lo(w.y); a1[3] += bf_hi(w.y);
        a1[4] += bf_lo(w.z); a1[5] += bf_hi(w.z);
        a1[6] += bf_lo(w.w); a1[7] += bf_hi(w.w);
      }
      if (e1 < end1) {
        int s = col[e1];
        uint4 w = ((const uint4*)(hb + (long)s * 64))[r];
        b0[0] += bf_lo(w.x); b0[1] += bf_hi(w.x);
        b0[2] += bf_lo(w.y); b0[3] += bf_hi(w.y);
        b0[4] += bf_lo(w.z); b0[5] += bf_hi(w.z);
        b0[6] += bf_lo(w.w); b0[7] += bf_hi(w.w);
      }
      if (e1 + 8 < end1) {
        int s = col[e1 + 8];
        uint4 w = ((const uint4*)(hb + (long)s * 64))[r];
        b1v[0] += bf_lo(w.x); b1v[1] += bf_hi(w.x);
        b1v[2] += bf_lo(w.y); b1v[3] += bf_hi(w.y);
        b1v[4] += bf_lo(w.z); b1v[5] += bf_hi(w.z);
        b1v[6] += bf_lo(w.w); b1v[7] += bf_hi(w.w);
      }
      e0 += 16; e1 += 16;
    }
#pragma unroll
    for (int j = 0; j < 8; ++j) { a0[j] += a1[j]; b0[j] += b1v[j]; }
#pragma unroll
    for (int m = 8; m <= 32; m <<= 1) {
#pragma unroll
      for (int j = 0; j < 8; ++j) {
        a0[j] += __shfl_xor(a0[j], m, 64);
        b0[j] += __shfl_xor(b0[j], m, 64);
      }
    }
    if (g == 0) {
      uint4 hv = ((const uint4*)(hb + (long)n0 * 64))[r];
      float v0 = fmaf(ep, bf_lo(hv.x), a0[0]), v1 = fmaf(ep, bf_hi(hv.x), a0[1]);
      float v2 = fmaf(ep, bf_lo(hv.y), a0[2]), v3 = fmaf(ep, bf_hi(hv.y), a0[3]);
      float v4 = fmaf(ep, bf_lo(hv.z), a0[4]), v5 = fmaf(ep, bf_hi(hv.z), a0[5]);
      float v6 = fmaf(ep, bf_lo(hv.w), a0[6]), v7 = fmaf(ep, bf_hi(hv.w), a0[7]);
      uintx4 w;
      w.x = pack_bf16(v0, v1); w.y = pack_bf16(v2, v3);
      w.z = pack_bf16(v4, v5); w.w = pack_bf16(v6, v7);
      __builtin_nontemporal_store(w, (uintx4*)(zb + (size_t)n0 * 64 + r * 8));
    } else if (g == 1 && n1 < N) {
      uint4 hv = ((const uint4*)(hb + (long)n1 * 64))[r];
      float v0 = fmaf(ep, bf_lo(hv.x), b0[0]), v1 = fmaf(ep, bf_hi(hv.x), b0[1]);
      float v2 = fmaf(ep, bf_lo(hv.y), b0[2]), v3 = fmaf(ep, bf_hi(hv.y), b0[3]);
      float v4 = fmaf(ep, bf_lo(hv.z), b0[4]), v5 = fmaf(ep, bf_hi(hv.z), b0[5]);
      float v6 = fmaf(ep, bf_lo(hv.w), b0[6]), v7 = fmaf(ep, bf_hi(hv.w), b0[7]);
      uintx4 w;
      w.x = pack_bf16(v0, v1); w.y = pack_bf16(v2, v3);
      w.z = pack_bf16(v4, v5); w.w = pack_bf16(v6, v7);
      __builtin_nontemporal_store(w, (uintx4*)(zb + (size_t)n1 * 64 + r * 8));
    }
  }
}

// ---------------------------------------------------------------------------
// MFMA MLP + fused mean-pool partial sums.
// skip1: A-frags computed in-kernel from z0 (scalar/node) + W1f + bn1 (t0
// fused). tls/hls share one 64x68 LDS buffer (disjoint lifetimes, wave-local
// rows until the final barrier).
// ---------------------------------------------------------------------------
__global__ __launch_bounds__(256) void mfma_mlp_kernel(
    const ushort* __restrict__ zb, const float* __restrict__ z0,
    const float* __restrict__ W1f, ushort* __restrict__ hout,
    const ushort* __restrict__ wp1, const ushort* __restrict__ wp2,
    const float* __restrict__ b1, const float* __restrict__ g1,
    const float* __restrict__ be1, const float* __restrict__ m1,
    const float* __restrict__ v1,
    const float* __restrict__ b2, const float* __restrict__ g2,
    const float* __restrict__ be2, const float* __restrict__ m2,
    const float* __restrict__ v2,
    const int* __restrict__ batch, float* __restrict__ pooled,
    int layer, int skip1, int N) {
  __shared__ float bnp[6][64];
  __shared__ float w1fl[64];
  __shared__ float sbuf[64][68];   // phase1: t rows; epilogue: h rows
  __shared__ int batchl[64];
  int tid = threadIdx.x;
  int blockbase = blockIdx.x * 64;
  if (tid < 64) {
    bnp[0][tid] = b1[tid];
    float s1 = g1[tid] * rsqrtf(v1[tid] + 1e-5f);
    bnp[1][tid] = s1;
    bnp[2][tid] = be1[tid] - m1[tid] * s1;
    bnp[3][tid] = b2[tid];
    float s2 = g2[tid] * rsqrtf(v2[tid] + 1e-5f);
    bnp[4][tid] = s2;
    bnp[5][tid] = be2[tid] - m2[tid] * s2;
    batchl[tid] = (blockbase + tid < N) ? batch[blockbase + tid] : -1;
    if (skip1) w1fl[tid] = W1f[tid];
  }
  __syncthreads();
  int wave = tid >> 6, lane = tid & 63;
  int q = lane >> 4, c = lane & 15;
  int base = blockbase + wave * 16;

  short8 ahi0, alo0, ahi1, alo1;
  if (!skip1) {
    // A from global bf16 z (nt: single-use stream); GEMM1 2-term
    {
      long row = base + c;
      if (row >= N) row = N - 1;
      const ushort* zr = zb + row * 64;
      ahi0 = __builtin_nontemporal_load((const short8*)(zr + q * 8));
      ahi1 = __builtin_nontemporal_load((const short8*)(zr + 32 + q * 8));
    }
    floatx4 acc[4];
#pragma unroll
    for (int nt = 0; nt < 4; ++nt) acc[nt] = (floatx4){0.f, 0.f, 0.f, 0.f};
#pragma unroll
    for (int nt = 0; nt < 4; ++nt) {
#pragma unroll
      for (int ks = 0; ks < 2; ++ks) {
        const ushort* fb = wp1 + ((nt * 2 + ks) * 2) * 512 + lane * 8;
        short8 bh = *(const short8*)fb;
        short8 bl = *(const short8*)(fb + 512);
        short8 ah = ks ? ahi1 : ahi0;
        acc[nt] = __builtin_amdgcn_mfma_f32_16x16x32_bf16(ah, bh, acc[nt], 0, 0, 0);
        acc[nt] = __builtin_amdgcn_mfma_f32_16x16x32_bf16(ah, bl, acc[nt], 0, 0, 0);
      }
    }
    // bn1 -> wave-local rows of sbuf -> rebuild A hi/lo
#pragma unroll
    for (int nt = 0; nt < 4; ++nt) {
      int feat = nt * 16 + c;
      float s1 = bnp[1][feat], o1 = bnp[2][feat], bb = bnp[0][feat];
#pragma unroll
      for (int r = 0; r < 4; ++r) {
        float y = fmaxf(acc[nt][r] + bb, 0.f);
        sbuf[wave * 16 + q * 4 + r][feat] = fmaf(y, s1, o1);
      }
    }
    float4 u0 = *(const float4*)&sbuf[wave * 16 + c][q * 8];
    float4 u1 = *(const float4*)&sbuf[wave * 16 + c][q * 8 + 4];
    split8(u0, u1, ahi0, alo0);
    u0 = *(const float4*)&sbuf[wave * 16 + c][32 + q * 8];
    u1 = *(const float4*)&sbuf[wave * 16 + c][32 + q * 8 + 4];
    split8(u0, u1, ahi1, alo1);
  } else {
    // fused t0: t[k] = bn1(relu(z0*W1f[k]+b1[k])), fp32 -> hi/lo
    long row = base + c;
    if (row >= N) row = N - 1;
    float zv = z0[row];
    float4 t00, t01, t10, t11;
    {
      float tv[8];
#pragma unroll
      for (int j = 0; j < 8; ++j) {
        int k = q * 8 + j;
        float y = fmaxf(fmaf(zv, w1fl[k], bnp[0][k]), 0.f);
        tv[j] = fmaf(y, bnp[1][k], bnp[2][k]);
      }
      t00 = make_float4(tv[0], tv[1], tv[2], tv[3]);
      t01 = make_float4(tv[4], tv[5], tv[6], tv[7]);
#pragma unroll
      for (int j = 0; j < 8; ++j) {
        int k = 32 + q * 8 + j;
        float y = fmaxf(fmaf(zv, w1fl[k], bnp[0][k]), 0.f);
        tv[j] = fmaf(y, bnp[1][k], bnp[2][k]);
      }
      t10 = make_float4(tv[0], tv[1], tv[2], tv[3]);
      t11 = make_float4(tv[4], tv[5], tv[6], tv[7]);
    }
    split8(t00, t01, ahi0, alo0);
    split8(t10, t11, ahi1, alo1);
  }

  // GEMM2: 3-term (A hi/lo available in both modes)
  floatx4 acc2[4];
#pragma unroll
  for (int nt = 0; nt < 4; ++nt) acc2[nt] = (floatx4){0.f, 0.f, 0.f, 0.f};
#pragma unroll
  for (int nt = 0; nt < 4; ++nt) {
#pragma unroll
    for (int ks = 0; ks < 2; ++ks) {
      const ushort* fb = wp2 + ((nt * 2 + ks) * 2) * 512 + lane * 8;
      short8 bh = *(const short8*)fb;
      short8 bl = *(const short8*)(fb + 512);
      short8 ah = ks ? ahi1 : ahi0;
      short8 al = ks ? alo1 : alo0;
      acc2[nt] = __builtin_amdgcn_mfma_f32_16x16x32_bf16(ah, bh, acc2[nt], 0, 0, 0);
      acc2[nt] = __builtin_amdgcn_mfma_f32_16x16x32_bf16(al, bh, acc2[nt], 0, 0, 0);
      acc2[nt] = __builtin_amdgcn_mfma_f32_16x16x32_bf16(ah, bl, acc2[nt], 0, 0, 0);
    }
  }

  // bn2 -> h bf16 store + LDS stage (sbuf reuse: wave-local rows) for pooling
#pragma unroll
  for (int nt = 0; nt < 4; ++nt) {
    int feat = nt * 16 + c;
    float s2 = bnp[4][feat], o2 = bnp[5][feat], bb = bnp[3][feat];
#pragma unroll
    for (int r = 0; r < 4; ++r) {
      int node = base + q * 4 + r;
      int li = wave * 16 + q * 4 + r;
      float val = 0.f;
      if (node < N) {
        float y = fmaxf(acc2[nt][r] + bb, 0.f);
        val = fmaf(y, s2, o2);
        hout[(long)node * 64 + feat] = f2bf(val);
      }
      sbuf[li][feat] = val;
    }
  }
  __syncthreads();

  // per-graph segment sums over this block's 64 nodes (batch sorted)
  if (tid < 64) {
    int j = tid;
    int nvalid = N - blockbase;
    if (nvalid > 64) nvalid = 64;
    int i = 0;
    while (i < nvalid) {
      int g = batchl[i];
      float s = 0.f;
      while (i < nvalid && batchl[i] == g) { s += sbuf[i][j]; ++i; }
      atomicAdd(&pooled[(size_t)g * 512 + layer * 64 + j], s);
    }
  }
}

__global__ void z0_kernel(const float* __restrict__ x, const int* __restrict__ rp,
                          const int* __restrict__ col, const float* __restrict__ eps,
                          float* __restrict__ z0, int N) {
  int n = blockIdx.x * blockDim.x + threadIdx.x;
  if (n >= N) return;
  int beg = rp[n], end = rp[n + 1];
  float a = 0.f;
  for (int e = beg; e < end; ++e) a += x[col[e]];
  z0[n] = fmaf(1.0f + eps[0], x[n], a);
}

__global__ __launch_bounds__(64) void final_kernel(
    const float* __restrict__ pooled, const int* __restrict__ gs,
    const float* __restrict__ lin1_w, const float* __restrict__ lin1_b,
    const float* __restrict__ lin2_w, const float* __restrict__ lin2_b,
    float* __restrict__ out, int G) {
  int g = blockIdx.x;
  int j = threadIdx.x;
  float inv = 1.0f / fmaxf((float)(gs[g + 1] - gs[g]), 1.0f);
  __shared__ float p[512];
  for (int t = j; t < 512; t += 64) p[t] = pooled[(long)g * 512 + t] * inv;
  __syncthreads();
  float a0 = lin1_b[j], a1 = 0.f, a2 = 0.f, a3 = 0.f;
  for (int k = 0; k < 512; k += 4) {
    a0 = fmaf(p[k + 0], lin1_w[(k + 0) * 64 + j], a0);
    a1 = fmaf(p[k + 1], lin1_w[(k + 1) * 64 + j], a1);
    a2 = fmaf(p[k + 2], lin1_w[(k + 2) * 64 + j], a2);
    a3 = fmaf(p[k + 3], lin1_w[(k + 3) * 64 + j], a3);
  }
  float hv = fmaxf((a0 + a1) + (a2 + a3), 0.f);
  __shared__ float hb[64];
  hb[j] = hv;
  __syncthreads();
  __shared__ float lg[3];
  if (j < 3) {
    float a = lin2_b[j];
#pragma unroll
    for (int k = 0; k < 64; ++k) a = fmaf(hb[k], lin2_w[k * 3 + j], a);
    lg[j] = a;
  }
  __syncthreads();
  if (j < 3) {
    float mx = fmaxf(fmaxf(lg[0], lg[1]), lg[2]);
    float lse = mx + logf(expf(lg[0] - mx) + expf(lg[1] - mx) + expf(lg[2] - mx));
    out[g * 3 + j] = lg[j] - lse;
  }
}

extern "C" void kernel_launch(void* const* d_in, const int* in_sizes, int n_in,
                              void* d_out, int out_size, void* d_ws, size_t ws_size,
                              hipStream_t stream) {
  const float* x        = (const float*)d_in[0];
  const int*   edge     = (const int*)d_in[1];
  const int*   batch    = (const int*)d_in[2];
  const float* eps      = (const float*)d_in[4];
  const float* W1_first = (const float*)d_in[5];
  const float* W1_rest  = (const float*)d_in[6];
  const float* b1       = (const float*)d_in[7];
  const float* g1       = (const float*)d_in[8];
  const float* be1      = (const float*)d_in[9];
  const float* m1       = (const float*)d_in[10];
  const float* v1       = (const float*)d_in[11];
  const float* W2       = (const float*)d_in[12];
  const float* b2       = (const float*)d_in[13];
  const float* g2       = (const float*)d_in[14];
  const float* be2      = (const float*)d_in[15];
  const float* m2       = (const float*)d_in[16];
  const float* v2       = (const float*)d_in[17];
  const float* lin1_w   = (const float*)d_in[18];
  const float* lin1_b   = (const float*)d_in[19];
  const float* lin2_w   = (const float*)d_in[20];
  const float* lin2_b   = (const float*)d_in[21];

  int N = in_sizes[0];
  int E = in_sizes[1] / 2;
  int G = out_size / 3;
  const int* esrc = edge;
  const int* edst = edge + E;
  int NB = (N + (1 << BBITS) - 1) >> BBITS;
  if (NB > 128) NB = 128;

  size_t off = 0;
  auto alloc = [&](size_t bytes) -> char* {
    char* p = (char*)d_ws + off;
    off += (bytes + 255) & ~(size_t)255;
    return p;
  };
  int SB = (N + 255) / 256;
  int*    deg    = (int*)alloc((size_t)N * 4);
  int*    rp     = (int*)alloc((size_t)(N + 1) * 4);
  int*    col    = (int*)alloc((size_t)E * 4);
  int*    bsum   = (int*)alloc((size_t)SB * 4);
  int*    boff   = (int*)alloc((size_t)SB * 4);
  int*    bc     = (int*)alloc((size_t)128 * 16 * 4);
  uint*   arena  = (uint*)alloc((size_t)NB * BCAP * 4);
  int*    gs     = (int*)alloc((size_t)(G + 1) * 4);
  ushort* wpack  = (ushort*)alloc((size_t)16 * 8192 * 2);
  float*  z0buf  = (float*)alloc((size_t)N * 4);
  ushort* zbuf   = (ushort*)alloc((size_t)N * 64 * 2);
  ushort* hA     = (ushort*)alloc((size_t)N * 64 * 2);
  ushort* hB     = (ushort*)alloc((size_t)N * 64 * 2);
  float*  pooled = (float*)alloc((size_t)G * 512 * 4);
  (void)ws_size;

  // atomic-free binned CSC build (packed arena)
  init_bc_kernel<<<1, 128, 0, stream>>>(bc, NB);
  int ebA = (E + 4095) / 4096;
  bin_edges_kernel<<<ebA, 1024, 0, stream>>>(esrc, edst, bc, arena, E);
  bucket_count_kernel<<<NB, 1024, 0, stream>>>(arena, bc, deg, N);
  scan_blocksums<<<SB, 256, 0, stream>>>(deg, bsum, N);
  scan_bsum<<<1, 1024, 0, stream>>>(bsum, boff, rp + N, SB);
  scan_final<<<SB, 256, 0, stream>>>(deg, boff, rp, N);
  bucket_scatter_kernel<<<NB, 1024, 0, stream>>>(arena, bc, rp, col, N);

  graph_bounds_kernel<<<SB, 256, 0, stream>>>(batch, gs, N, G);
  prepack_w_kernel<<<16, 256, 0, stream>>>(W1_rest, W2, wpack);
  (void)hipMemsetAsync(pooled, 0, (size_t)G * 512 * 4, stream);

  int nb = (N + 63) / 64;
  z0_kernel<<<SB, 256, 0, stream>>>(x, rp, col, eps, z0buf, N);
  mfma_mlp_kernel<<<nb, 256, 0, stream>>>(zbuf, z0buf, W1_first, hA,
      wpack, wpack + 8192,
      b1, g1, be1, m1, v1, b2, g2, be2, m2, v2, batch, pooled, 0, 1, N);

  ushort* hin = hA;
  ushort* hout = hB;
  for (int i = 1; i < 8; ++i) {
    agg_kernel<<<2048, 256, 0, stream>>>(hin, rp, col, eps, i, zbuf, N);
    mfma_mlp_kernel<<<nb, 256, 0, stream>>>(zbuf, z0buf, W1_first, hout,
        wpack + (size_t)(2 * i) * 8192, wpack + (size_t)(2 * i + 1) * 8192,
        b1 + i * 64, g1 + i * 64, be1 + i * 64, m1 + i * 64, v1 + i * 64,
        b2 + i * 64, g2 + i * 64, be2 + i * 64, m2 + i * 64, v2 + i * 64,
        batch, pooled, i, 0, N);
    ushort* t = hin; hin = hout; hout = t;
  }
  final_kernel<<<G, 64, 0, stream>>>(pooled, gs, lin1_w, lin1_b,
                                     lin2_w, lin2_b, (float*)d_out, G);
}

// Round 16
// 636.253 us; speedup vs baseline: 3.1446x; 1.0078x over previous
//
#include <hip/hip_runtime.h>
#include <hip/hip_bf16.h>
#include <math.h>

// ---------------------------------------------------------------------------
// GIN + JumpingKnowledge(cat) + mean-pool + 2-layer head, eval mode.
// R16 (on R15, 641us): mfma_mlp restructured (everything else frozen):
//  - 128 nodes/block, 512 threads (8 waves x 16-node strip): halves block
//    count, amortizes prologue/epilogue.
//  - h stores vectorized via LDS stage (dwordx4 chunks, 2/thread) replacing
//    16 scalar ushort stores per thread.
//  - pooling epilogue parallelized: 256 threads (feat x quarter), 32-row
//    scans, per-quarter segment atomics.
// Keeps: R15 agg/build/z0-fusion/bf16 z/nt streams/split-bf16 MFMA.
// ---------------------------------------------------------------------------

typedef unsigned int uint;
typedef unsigned short ushort;
typedef __attribute__((ext_vector_type(8))) short short8;
typedef __attribute__((ext_vector_type(4))) float floatx4;
typedef __attribute__((ext_vector_type(4))) uint uintx4;

#define BBITS 10                 // 1024 nodes per bucket
#define BCAP 20480               // arena capacity per bucket
#define BMASK ((1 << BBITS) - 1)

__device__ __forceinline__ float bf_lo(uint w) { return __uint_as_float(w << 16); }
__device__ __forceinline__ float bf_hi(uint w) { return __uint_as_float(w & 0xffff0000u); }

__device__ __forceinline__ ushort f2bf(float x) {
  __hip_bfloat16 h = __float2bfloat16(x);
  return *(ushort*)&h;
}
__device__ __forceinline__ float bf2f(ushort u) { return __uint_as_float((uint)u << 16); }

__device__ __forceinline__ uint pack_bf16(float a, float b) {
  return (uint)f2bf(a) | ((uint)f2bf(b) << 16);
}

__device__ __forceinline__ void split8(float4 u0, float4 u1, short8& hi, short8& lo) {
  float v0 = u0.x, v1 = u0.y, v2 = u0.z, v3 = u0.w;
  float v4 = u1.x, v5 = u1.y, v6 = u1.z, v7 = u1.w;
  ushort h0 = f2bf(v0), h1 = f2bf(v1), h2 = f2bf(v2), h3 = f2bf(v3);
  ushort h4 = f2bf(v4), h5 = f2bf(v5), h6 = f2bf(v6), h7 = f2bf(v7);
  hi[0] = (short)h0; hi[1] = (short)h1; hi[2] = (short)h2; hi[3] = (short)h3;
  hi[4] = (short)h4; hi[5] = (short)h5; hi[6] = (short)h6; hi[7] = (short)h7;
  lo[0] = (short)f2bf(v0 - bf2f(h0)); lo[1] = (short)f2bf(v1 - bf2f(h1));
  lo[2] = (short)f2bf(v2 - bf2f(h2)); lo[3] = (short)f2bf(v3 - bf2f(h3));
  lo[4] = (short)f2bf(v4 - bf2f(h4)); lo[5] = (short)f2bf(v5 - bf2f(h5));
  lo[6] = (short)f2bf(v6 - bf2f(h6)); lo[7] = (short)f2bf(v7 - bf2f(h7));
}

// ---- atomic-free binned CSC build (packed arena) ---------------------------

__global__ void init_bc_kernel(int* __restrict__ bc, int NB) {
  int b = threadIdx.x;
  if (b < NB) bc[b * 16] = b * BCAP;
}

__global__ __launch_bounds__(1024) void bin_edges_kernel(
    const int* __restrict__ src, const int* __restrict__ dst, int* __restrict__ bc,
    uint* __restrict__ arena, int E) {
  __shared__ int cnt[128], base[128];
  for (long chunk = (long)blockIdx.x * 4096; chunk < E; chunk += (long)gridDim.x * 4096) {
    if (threadIdx.x < 128) cnt[threadIdx.x] = 0;
    __syncthreads();
    uint v[4];
    int b[4], r[4];
#pragma unroll
    for (int u = 0; u < 4; ++u) {
      long e = chunk + threadIdx.x + u * 1024;
      if (e < E) {
        int s = src[e];
        int d = dst[e];
        b[u] = d >> BBITS;
        v[u] = ((uint)s << BBITS) | (uint)(d & BMASK);
        r[u] = atomicAdd(&cnt[b[u]], 1);
      }
    }
    __syncthreads();
    if (threadIdx.x < 128)
      base[threadIdx.x] = cnt[threadIdx.x] ? atomicAdd(&bc[threadIdx.x * 16], cnt[threadIdx.x]) : 0;
    __syncthreads();
#pragma unroll
    for (int u = 0; u < 4; ++u) {
      long e = chunk + threadIdx.x + u * 1024;
      if (e < E) arena[base[b[u]] + r[u]] = v[u];
    }
    __syncthreads();
  }
}

__global__ __launch_bounds__(1024) void bucket_count_kernel(
    const uint* __restrict__ arena, const int* __restrict__ bc,
    int* __restrict__ deg, int N) {
  __shared__ int hist[1 << BBITS];
  int b = blockIdx.x;
  int lo = b << BBITS;
  int hi = min(lo + (1 << BBITS), N);
  hist[threadIdx.x] = 0;
  __syncthreads();
  int cnt = bc[b * 16] - b * BCAP;
  const uint* ad = arena + (size_t)b * BCAP;
  for (int i = threadIdx.x; i < cnt; i += 1024) atomicAdd(&hist[ad[i] & BMASK], 1);
  __syncthreads();
  if (lo + (int)threadIdx.x < hi) deg[lo + threadIdx.x] = hist[threadIdx.x];
}

__global__ __launch_bounds__(1024) void bucket_scatter_kernel(
    const uint* __restrict__ arena, const int* __restrict__ bc,
    const int* __restrict__ rp, int* __restrict__ col, int N) {
  __shared__ int cur[1 << BBITS];
  int b = blockIdx.x;
  int lo = b << BBITS;
  int hi = min(lo + (1 << BBITS), N);
  if (lo + (int)threadIdx.x < hi) cur[threadIdx.x] = rp[lo + threadIdx.x];
  __syncthreads();
  int cnt = bc[b * 16] - b * BCAP;
  const uint* ad = arena + (size_t)b * BCAP;
  for (int i = threadIdx.x; i < cnt; i += 1024) {
    uint v = ad[i];
    int pos = atomicAdd(&cur[v & BMASK], 1);
    col[pos] = (int)(v >> BBITS);
  }
}

// ---- scan -----------------------------------------------------------------
__global__ void scan_blocksums(const int* __restrict__ deg, int* __restrict__ bsum, int N) {
  __shared__ int red[256];
  int i = blockIdx.x * 256 + threadIdx.x;
  red[threadIdx.x] = (i < N) ? deg[i] : 0;
  __syncthreads();
  for (int off = 128; off > 0; off >>= 1) {
    if (threadIdx.x < off) red[threadIdx.x] += red[threadIdx.x + off];
    __syncthreads();
  }
  if (threadIdx.x == 0) bsum[blockIdx.x] = red[0];
}

__global__ void scan_bsum(const int* __restrict__ bsum, int* __restrict__ boff,
                          int* __restrict__ rp_last, int B) {
  __shared__ int tmp[1024];
  int t = threadIdx.x;
  int v = (t < B) ? bsum[t] : 0;
  tmp[t] = v;
  __syncthreads();
  for (int off = 1; off < 1024; off <<= 1) {
    int u = (t >= off) ? tmp[t - off] : 0;
    __syncthreads();
    tmp[t] += u;
    __syncthreads();
  }
  if (t < B) boff[t] = tmp[t] - v;
  if (t == 1023) *rp_last = tmp[1023];
}

__global__ void scan_final(const int* __restrict__ deg, const int* __restrict__ boff,
                           int* __restrict__ rp, int N) {
  __shared__ int tmp[256];
  int i = blockIdx.x * 256 + threadIdx.x;
  int v = (i < N) ? deg[i] : 0;
  tmp[threadIdx.x] = v;
  __syncthreads();
  for (int off = 1; off < 256; off <<= 1) {
    int u = (threadIdx.x >= off) ? tmp[threadIdx.x - off] : 0;
    __syncthreads();
    tmp[threadIdx.x] += u;
    __syncthreads();
  }
  if (i < N) rp[i] = boff[blockIdx.x] + tmp[threadIdx.x] - v;
}

__global__ void graph_bounds_kernel(const int* __restrict__ batch, int* __restrict__ gs,
                                    int N, int G) {
  int n = blockIdx.x * 256 + threadIdx.x;
  if (n >= N) return;
  int b = batch[n];
  int bp = (n == 0) ? -1 : batch[n - 1];
  for (int g = bp + 1; g <= b; ++g) gs[g] = n;
  if (n == N - 1)
    for (int g = b + 1; g <= G; ++g) gs[g] = N;
}

// Prepack W1/W2 into MFMA B-fragment order, split hi/lo bf16.
__global__ void prepack_w_kernel(const float* __restrict__ W1_rest,
                                 const float* __restrict__ W2, ushort* __restrict__ wp) {
  int l = blockIdx.x >> 1, g = blockIdx.x & 1;
  const float* W;
  if (g == 0) {
    if (l == 0) return;
    W = W1_rest + (size_t)(l - 1) * 4096;
  } else {
    W = W2 + (size_t)l * 4096;
  }
  ushort* out = wp + (size_t)(l * 2 + g) * 8192;
  for (int idx = threadIdx.x; idx < 4096; idx += blockDim.x) {
    int j = idx & 7, lane = (idx >> 3) & 63, ks = (idx >> 9) & 1, nt = (idx >> 10) & 3;
    int k = ks * 32 + (lane >> 4) * 8 + j;
    int n = nt * 16 + (lane & 15);
    float w = W[k * 64 + n];
    ushort hi = f2bf(w);
    ushort lo = f2bf(w - bf2f(hi));
    size_t base = (size_t)((nt * 2 + ks) * 2) * 512 + lane * 8 + j;
    out[base] = hi;
    out[base + 512] = lo;
  }
}

// z[n][:] = (1+eps_l)*h[n][:] + sum_e h[col[e]][:]   (h bf16, z bf16 out)
__global__ __launch_bounds__(256, 8) void agg_kernel(
    const ushort* __restrict__ hb, const int* __restrict__ rp,
    const int* __restrict__ col, const float* __restrict__ eps,
    int layer, ushort* __restrict__ zb, int N) {
  int lane = threadIdx.x & 63;
  int g = lane >> 3;
  int r = lane & 7;
  int wave = blockIdx.x * (blockDim.x >> 6) + (threadIdx.x >> 6);
  int nwaves = gridDim.x * (blockDim.x >> 6);
  float ep = 1.0f + eps[layer];
  for (int n = wave * 2; n < N; n += nwaves * 2) {
    int n0 = __builtin_amdgcn_readfirstlane(n);
    int n1 = n0 + 1;
    int beg0 = rp[n0];
    int end0 = rp[n0 + 1];
    int end1 = (n1 < N) ? rp[n1 + 1] : end0;
    float a0[8] = {0.f, 0.f, 0.f, 0.f, 0.f, 0.f, 0.f, 0.f};
    float a1[8] = {0.f, 0.f, 0.f, 0.f, 0.f, 0.f, 0.f, 0.f};
    float b0[8] = {0.f, 0.f, 0.f, 0.f, 0.f, 0.f, 0.f, 0.f};
    float b1v[8] = {0.f, 0.f, 0.f, 0.f, 0.f, 0.f, 0.f, 0.f};
    int e0 = beg0 + g;
    int e1 = end0 + g;
    while (e0 < end0 || e1 < end1) {
      if (e0 < end0) {
        int s = col[e0];
        uint4 w = ((const uint4*)(hb + (long)s * 64))[r];
        a0[0] += bf_lo(w.x); a0[1] += bf_hi(w.x);
        a0[2] += bf_lo(w.y); a0[3] += bf_hi(w.y);
        a0[4] += bf_lo(w.z); a0[5] += bf_hi(w.z);
        a0[6] += bf_lo(w.w); a0[7] += bf_hi(w.w);
      }
      if (e0 + 8 < end0) {
        int s = col[e0 + 8];
        uint4 w = ((const uint4*)(hb + (long)s * 64))[r];
        a1[0] += bf_lo(w.x); a1[1] += bf_hi(w.x);
        a1[2] += bf_lo(w.y); a1[3] += bf_hi(w.y);
        a1[4] += bf_lo(w.z); a1[5] += bf_hi(w.z);
        a1[6] += bf_lo(w.w); a1[7] += bf_hi(w.w);
      }
      if (e1 < end1) {
        int s = col[e1];
        uint4 w = ((const uint4*)(hb + (long)s * 64))[r];
        b0[0] += bf_lo(w.x); b0[1] += bf_hi(w.x);
        b0[2] += bf_lo(w.y); b0[3] += bf_hi(w.y);
        b0[4] += bf_lo(w.z); b0[5] += bf_hi(w.z);
        b0[6] += bf_lo(w.w); b0[7] += bf_hi(w.w);
      }
      if (e1 + 8 < end1) {
        int s = col[e1 + 8];
        uint4 w = ((const uint4*)(hb + (long)s * 64))[r];
        b1v[0] += bf_lo(w.x); b1v[1] += bf_hi(w.x);
        b1v[2] += bf_lo(w.y); b1v[3] += bf_hi(w.y);
        b1v[4] += bf_lo(w.z); b1v[5] += bf_hi(w.z);
        b1v[6] += bf_lo(w.w); b1v[7] += bf_hi(w.w);
      }
      e0 += 16; e1 += 16;
    }
#pragma unroll
    for (int j = 0; j < 8; ++j) { a0[j] += a1[j]; b0[j] += b1v[j]; }
#pragma unroll
    for (int m = 8; m <= 32; m <<= 1) {
#pragma unroll
      for (int j = 0; j < 8; ++j) {
        a0[j] += __shfl_xor(a0[j], m, 64);
        b0[j] += __shfl_xor(b0[j], m, 64);
      }
    }
    if (g == 0) {
      uint4 hv = ((const uint4*)(hb + (long)n0 * 64))[r];
      float v0 = fmaf(ep, bf_lo(hv.x), a0[0]), v1 = fmaf(ep, bf_hi(hv.x), a0[1]);
      float v2 = fmaf(ep, bf_lo(hv.y), a0[2]), v3 = fmaf(ep, bf_hi(hv.y), a0[3]);
      float v4 = fmaf(ep, bf_lo(hv.z), a0[4]), v5 = fmaf(ep, bf_hi(hv.z), a0[5]);
      float v6 = fmaf(ep, bf_lo(hv.w), a0[6]), v7 = fmaf(ep, bf_hi(hv.w), a0[7]);
      uintx4 w;
      w.x = pack_bf16(v0, v1); w.y = pack_bf16(v2, v3);
      w.z = pack_bf16(v4, v5); w.w = pack_bf16(v6, v7);
      __builtin_nontemporal_store(w, (uintx4*)(zb + (size_t)n0 * 64 + r * 8));
    } else if (g == 1 && n1 < N) {
      uint4 hv = ((const uint4*)(hb + (long)n1 * 64))[r];
      float v0 = fmaf(ep, bf_lo(hv.x), b0[0]), v1 = fmaf(ep, bf_hi(hv.x), b0[1]);
      float v2 = fmaf(ep, bf_lo(hv.y), b0[2]), v3 = fmaf(ep, bf_hi(hv.y), b0[3]);
      float v4 = fmaf(ep, bf_lo(hv.z), b0[4]), v5 = fmaf(ep, bf_hi(hv.z), b0[5]);
      float v6 = fmaf(ep, bf_lo(hv.w), b0[6]), v7 = fmaf(ep, bf_hi(hv.w), b0[7]);
      uintx4 w;
      w.x = pack_bf16(v0, v1); w.y = pack_bf16(v2, v3);
      w.z = pack_bf16(v4, v5); w.w = pack_bf16(v6, v7);
      __builtin_nontemporal_store(w, (uintx4*)(zb + (size_t)n1 * 64 + r * 8));
    }
  }
}

// ---------------------------------------------------------------------------
// MFMA MLP + fused mean-pool. 128 nodes/block, 512 threads (8 waves x
// 16-node strip). Epilogue: vals staged in sbuf -> barrier -> vectorized
// dwordx4 h stores (2/thread) + feat x quarter parallel segment sums.
// ---------------------------------------------------------------------------
__global__ __launch_bounds__(512) void mfma_mlp_kernel(
    const ushort* __restrict__ zb, const float* __restrict__ z0,
    const float* __restrict__ W1f, ushort* __restrict__ hout,
    const ushort* __restrict__ wp1, const ushort* __restrict__ wp2,
    const float* __restrict__ b1, const float* __restrict__ g1,
    const float* __restrict__ be1, const float* __restrict__ m1,
    const float* __restrict__ v1,
    const float* __restrict__ b2, const float* __restrict__ g2,
    const float* __restrict__ be2, const float* __restrict__ m2,
    const float* __restrict__ v2,
    const int* __restrict__ batch, float* __restrict__ pooled,
    int layer, int skip1, int N) {
  __shared__ float bnp[6][64];
  __shared__ float w1fl[64];
  __shared__ float sbuf[128][68];  // phase1: t rows (wave-local); epilogue: h rows
  __shared__ int batchl[128];
  int tid = threadIdx.x;
  int blockbase = blockIdx.x * 128;
  if (tid < 64) {
    bnp[0][tid] = b1[tid];
    float s1 = g1[tid] * rsqrtf(v1[tid] + 1e-5f);
    bnp[1][tid] = s1;
    bnp[2][tid] = be1[tid] - m1[tid] * s1;
    bnp[3][tid] = b2[tid];
    float s2 = g2[tid] * rsqrtf(v2[tid] + 1e-5f);
    bnp[4][tid] = s2;
    bnp[5][tid] = be2[tid] - m2[tid] * s2;
    if (skip1) w1fl[tid] = W1f[tid];
  }
  if (tid < 128) batchl[tid] = (blockbase + tid < N) ? batch[blockbase + tid] : -1;
  __syncthreads();
  int wave = tid >> 6, lane = tid & 63;
  int q = lane >> 4, c = lane & 15;
  int base = blockbase + wave * 16;
  int srow = wave * 16;  // this wave's strip base row in sbuf

  short8 ahi0, alo0, ahi1, alo1;
  if (!skip1) {
    {
      long row = base + c;
      if (row >= N) row = N - 1;
      const ushort* zr = zb + row * 64;
      ahi0 = __builtin_nontemporal_load((const short8*)(zr + q * 8));
      ahi1 = __builtin_nontemporal_load((const short8*)(zr + 32 + q * 8));
    }
    floatx4 acc[4];
#pragma unroll
    for (int nt = 0; nt < 4; ++nt) acc[nt] = (floatx4){0.f, 0.f, 0.f, 0.f};
#pragma unroll
    for (int nt = 0; nt < 4; ++nt) {
#pragma unroll
      for (int ks = 0; ks < 2; ++ks) {
        const ushort* fb = wp1 + ((nt * 2 + ks) * 2) * 512 + lane * 8;
        short8 bh = *(const short8*)fb;
        short8 bl = *(const short8*)(fb + 512);
        short8 ah = ks ? ahi1 : ahi0;
        acc[nt] = __builtin_amdgcn_mfma_f32_16x16x32_bf16(ah, bh, acc[nt], 0, 0, 0);
        acc[nt] = __builtin_amdgcn_mfma_f32_16x16x32_bf16(ah, bl, acc[nt], 0, 0, 0);
      }
    }
#pragma unroll
    for (int nt = 0; nt < 4; ++nt) {
      int feat = nt * 16 + c;
      float s1 = bnp[1][feat], o1 = bnp[2][feat], bb = bnp[0][feat];
#pragma unroll
      for (int r = 0; r < 4; ++r) {
        float y = fmaxf(acc[nt][r] + bb, 0.f);
        sbuf[srow + q * 4 + r][feat] = fmaf(y, s1, o1);
      }
    }
    float4 u0 = *(const float4*)&sbuf[srow + c][q * 8];
    float4 u1 = *(const float4*)&sbuf[srow + c][q * 8 + 4];
    split8(u0, u1, ahi0, alo0);
    u0 = *(const float4*)&sbuf[srow + c][32 + q * 8];
    u1 = *(const float4*)&sbuf[srow + c][32 + q * 8 + 4];
    split8(u0, u1, ahi1, alo1);
  } else {
    long row = base + c;
    if (row >= N) row = N - 1;
    float zv = z0[row];
    float4 t00, t01, t10, t11;
    {
      float tv[8];
#pragma unroll
      for (int j = 0; j < 8; ++j) {
        int k = q * 8 + j;
        float y = fmaxf(fmaf(zv, w1fl[k], bnp[0][k]), 0.f);
        tv[j] = fmaf(y, bnp[1][k], bnp[2][k]);
      }
      t00 = make_float4(tv[0], tv[1], tv[2], tv[3]);
      t01 = make_float4(tv[4], tv[5], tv[6], tv[7]);
#pragma unroll
      for (int j = 0; j < 8; ++j) {
        int k = 32 + q * 8 + j;
        float y = fmaxf(fmaf(zv, w1fl[k], bnp[0][k]), 0.f);
        tv[j] = fmaf(y, bnp[1][k], bnp[2][k]);
      }
      t10 = make_float4(tv[0], tv[1], tv[2], tv[3]);
      t11 = make_float4(tv[4], tv[5], tv[6], tv[7]);
    }
    split8(t00, t01, ahi0, alo0);
    split8(t10, t11, ahi1, alo1);
  }

  // GEMM2: 3-term
  floatx4 acc2[4];
#pragma unroll
  for (int nt = 0; nt < 4; ++nt) acc2[nt] = (floatx4){0.f, 0.f, 0.f, 0.f};
#pragma unroll
  for (int nt = 0; nt < 4; ++nt) {
#pragma unroll
    for (int ks = 0; ks < 2; ++ks) {
      const ushort* fb = wp2 + ((nt * 2 + ks) * 2) * 512 + lane * 8;
      short8 bh = *(const short8*)fb;
      short8 bl = *(const short8*)(fb + 512);
      short8 ah = ks ? ahi1 : ahi0;
      short8 al = ks ? alo1 : alo0;
      acc2[nt] = __builtin_amdgcn_mfma_f32_16x16x32_bf16(ah, bh, acc2[nt], 0, 0, 0);
      acc2[nt] = __builtin_amdgcn_mfma_f32_16x16x32_bf16(al, bh, acc2[nt], 0, 0, 0);
      acc2[nt] = __builtin_amdgcn_mfma_f32_16x16x32_bf16(ah, bl, acc2[nt], 0, 0, 0);
    }
  }

  // bn2 -> stage vals in sbuf (wave-local rows)
#pragma unroll
  for (int nt = 0; nt < 4; ++nt) {
    int feat = nt * 16 + c;
    float s2 = bnp[4][feat], o2 = bnp[5][feat], bb = bnp[3][feat];
#pragma unroll
    for (int r = 0; r < 4; ++r) {
      int node = base + q * 4 + r;
      float val = 0.f;
      if (node < N) {
        float y = fmaxf(acc2[nt][r] + bb, 0.f);
        val = fmaf(y, s2, o2);
      }
      sbuf[srow + q * 4 + r][feat] = val;
    }
  }
  __syncthreads();

  // vectorized h stores: 128 rows x 8 chunks of 16B; 2 chunks/thread
#pragma unroll
  for (int it = 0; it < 2; ++it) {
    int chunk = tid + it * 512;
    int row = chunk >> 3, c8 = chunk & 7;
    int node = blockbase + row;
    if (node < N) {
      const float* sp = &sbuf[row][c8 * 8];
      uintx4 w;
      w.x = pack_bf16(sp[0], sp[1]);
      w.y = pack_bf16(sp[2], sp[3]);
      w.z = pack_bf16(sp[4], sp[5]);
      w.w = pack_bf16(sp[6], sp[7]);
      *(uintx4*)(hout + (long)node * 64 + c8 * 8) = w;
    }
  }

  // parallel segment sums: 256 threads = feat(64) x quarter(4), 32 rows each
  if (tid < 256) {
    int j = tid & 63;
    int quarter = tid >> 6;
    int nvalid = N - blockbase;
    if (nvalid > 128) nvalid = 128;
    int i = quarter * 32;
    int iend = i + 32;
    if (iend > nvalid) iend = nvalid;
    while (i < iend) {
      int g = batchl[i];
      float s = 0.f;
      while (i < iend && batchl[i] == g) { s += sbuf[i][j]; ++i; }
      atomicAdd(&pooled[(size_t)g * 512 + layer * 64 + j], s);
    }
  }
}

__global__ void z0_kernel(const float* __restrict__ x, const int* __restrict__ rp,
                          const int* __restrict__ col, const float* __restrict__ eps,
                          float* __restrict__ z0, int N) {
  int n = blockIdx.x * blockDim.x + threadIdx.x;
  if (n >= N) return;
  int beg = rp[n], end = rp[n + 1];
  float a = 0.f;
  for (int e = beg; e < end; ++e) a += x[col[e]];
  z0[n] = fmaf(1.0f + eps[0], x[n], a);
}

__global__ __launch_bounds__(64) void final_kernel(
    const float* __restrict__ pooled, const int* __restrict__ gs,
    const float* __restrict__ lin1_w, const float* __restrict__ lin1_b,
    const float* __restrict__ lin2_w, const float* __restrict__ lin2_b,
    float* __restrict__ out, int G) {
  int g = blockIdx.x;
  int j = threadIdx.x;
  float inv = 1.0f / fmaxf((float)(gs[g + 1] - gs[g]), 1.0f);
  __shared__ float p[512];
  for (int t = j; t < 512; t += 64) p[t] = pooled[(long)g * 512 + t] * inv;
  __syncthreads();
  float a0 = lin1_b[j], a1 = 0.f, a2 = 0.f, a3 = 0.f;
  for (int k = 0; k < 512; k += 4) {
    a0 = fmaf(p[k + 0], lin1_w[(k + 0) * 64 + j], a0);
    a1 = fmaf(p[k + 1], lin1_w[(k + 1) * 64 + j], a1);
    a2 = fmaf(p[k + 2], lin1_w[(k + 2) * 64 + j], a2);
    a3 = fmaf(p[k + 3], lin1_w[(k + 3) * 64 + j], a3);
  }
  float hv = fmaxf((a0 + a1) + (a2 + a3), 0.f);
  __shared__ float hb[64];
  hb[j] = hv;
  __syncthreads();
  __shared__ float lg[3];
  if (j < 3) {
    float a = lin2_b[j];
#pragma unroll
    for (int k = 0; k < 64; ++k) a = fmaf(hb[k], lin2_w[k * 3 + j], a);
    lg[j] = a;
  }
  __syncthreads();
  if (j < 3) {
    float mx = fmaxf(fmaxf(lg[0], lg[1]), lg[2]);
    float lse = mx + logf(expf(lg[0] - mx) + expf(lg[1] - mx) + expf(lg[2] - mx));
    out[g * 3 + j] = lg[j] - lse;
  }
}

extern "C" void kernel_launch(void* const* d_in, const int* in_sizes, int n_in,
                              void* d_out, int out_size, void* d_ws, size_t ws_size,
                              hipStream_t stream) {
  const float* x        = (const float*)d_in[0];
  const int*   edge     = (const int*)d_in[1];
  const int*   batch    = (const int*)d_in[2];
  const float* eps      = (const float*)d_in[4];
  const float* W1_first = (const float*)d_in[5];
  const float* W1_rest  = (const float*)d_in[6];
  const float* b1       = (const float*)d_in[7];
  const float* g1       = (const float*)d_in[8];
  const float* be1      = (const float*)d_in[9];
  const float* m1       = (const float*)d_in[10];
  const float* v1       = (const float*)d_in[11];
  const float* W2       = (const float*)d_in[12];
  const float* b2       = (const float*)d_in[13];
  const float* g2       = (const float*)d_in[14];
  const float* be2      = (const float*)d_in[15];
  const float* m2       = (const float*)d_in[16];
  const float* v2       = (const float*)d_in[17];
  const float* lin1_w   = (const float*)d_in[18];
  const float* lin1_b   = (const float*)d_in[19];
  const float* lin2_w   = (const float*)d_in[20];
  const float* lin2_b   = (const float*)d_in[21];

  int N = in_sizes[0];
  int E = in_sizes[1] / 2;
  int G = out_size / 3;
  const int* esrc = edge;
  const int* edst = edge + E;
  int NB = (N + (1 << BBITS) - 1) >> BBITS;
  if (NB > 128) NB = 128;

  size_t off = 0;
  auto alloc = [&](size_t bytes) -> char* {
    char* p = (char*)d_ws + off;
    off += (bytes + 255) & ~(size_t)255;
    return p;
  };
  int SB = (N + 255) / 256;
  int*    deg    = (int*)alloc((size_t)N * 4);
  int*    rp     = (int*)alloc((size_t)(N + 1) * 4);
  int*    col    = (int*)alloc((size_t)E * 4);
  int*    bsum   = (int*)alloc((size_t)SB * 4);
  int*    boff   = (int*)alloc((size_t)SB * 4);
  int*    bc     = (int*)alloc((size_t)128 * 16 * 4);
  uint*   arena  = (uint*)alloc((size_t)NB * BCAP * 4);
  int*    gs     = (int*)alloc((size_t)(G + 1) * 4);
  ushort* wpack  = (ushort*)alloc((size_t)16 * 8192 * 2);
  float*  z0buf  = (float*)alloc((size_t)N * 4);
  ushort* zbuf   = (ushort*)alloc((size_t)N * 64 * 2);
  ushort* hA     = (ushort*)alloc((size_t)N * 64 * 2);
  ushort* hB     = (ushort*)alloc((size_t)N * 64 * 2);
  float*  pooled = (float*)alloc((size_t)G * 512 * 4);
  (void)ws_size;

  // atomic-free binned CSC build (packed arena)
  init_bc_kernel<<<1, 128, 0, stream>>>(bc, NB);
  int ebA = (E + 4095) / 4096;
  bin_edges_kernel<<<ebA, 1024, 0, stream>>>(esrc, edst, bc, arena, E);
  bucket_count_kernel<<<NB, 1024, 0, stream>>>(arena, bc, deg, N);
  scan_blocksums<<<SB, 256, 0, stream>>>(deg, bsum, N);
  scan_bsum<<<1, 1024, 0, stream>>>(bsum, boff, rp + N, SB);
  scan_final<<<SB, 256, 0, stream>>>(deg, boff, rp, N);
  bucket_scatter_kernel<<<NB, 1024, 0, stream>>>(arena, bc, rp, col, N);

  graph_bounds_kernel<<<SB, 256, 0, stream>>>(batch, gs, N, G);
  prepack_w_kernel<<<16, 256, 0, stream>>>(W1_rest, W2, wpack);
  (void)hipMemsetAsync(pooled, 0, (size_t)G * 512 * 4, stream);

  int nb = (N + 127) / 128;
  z0_kernel<<<SB, 256, 0, stream>>>(x, rp, col, eps, z0buf, N);
  mfma_mlp_kernel<<<nb, 512, 0, stream>>>(zbuf, z0buf, W1_first, hA,
      wpack, wpack + 8192,
      b1, g1, be1, m1, v1, b2, g2, be2, m2, v2, batch, pooled, 0, 1, N);

  ushort* hin = hA;
  ushort* hout = hB;
  for (int i = 1; i < 8; ++i) {
    agg_kernel<<<2048, 256, 0, stream>>>(hin, rp, col, eps, i, zbuf, N);
    mfma_mlp_kernel<<<nb, 512, 0, stream>>>(zbuf, z0buf, W1_first, hout,
        wpack + (size_t)(2 * i) * 8192, wpack + (size_t)(2 * i + 1) * 8192,
        b1 + i * 64, g1 + i * 64, be1 + i * 64, m1 + i * 64, v1 + i * 64,
        b2 + i * 64, g2 + i * 64, be2 + i * 64, m2 + i * 64, v2 + i * 64,
        batch, pooled, i, 0, N);
    ushort* t = hin; hin = hout; hout = t;
  }
  final_kernel<<<G, 64, 0, stream>>>(pooled, gs, lin1_w, lin1_b,
                                     lin2_w, lin2_b, (float*)d_out, G);
}